// Round 8
// baseline (349.497 us; speedup 1.0000x reference)
//
#include <hip/hip_runtime.h>

typedef __attribute__((ext_vector_type(8))) short short8;
typedef __attribute__((ext_vector_type(4))) float f32x4;
typedef unsigned short u16;

#define T_SEQ 2048
#define C_DIM 2048

static __device__ __forceinline__ u16 f2bf(float f){
  unsigned u = __float_as_uint(f);
  u = (u + 0x7fffu + ((u >> 16) & 1u)) >> 16;
  return (u16)u;
}

__global__ void cvt_kernel(const float* __restrict__ in, u16* __restrict__ out, int n4){
  int idx = blockIdx.x * blockDim.x + threadIdx.x;
  int stride = gridDim.x * blockDim.x;
  for (int i = idx; i < n4; i += stride){
    float4 v = ((const float4*)in)[i];
    ushort4 o;
    o.x = f2bf(v.x); o.y = f2bf(v.y); o.z = f2bf(v.z); o.w = f2bf(v.w);
    ((ushort4*)out)[i] = o;
  }
}

__device__ __forceinline__ void gl_lds16(const void* g, void* l){
  __builtin_amdgcn_global_load_lds(
      (const __attribute__((address_space(1))) unsigned int*)g,
      (__attribute__((address_space(3))) unsigned int*)l,
      16, 0, 0);
}

// ---------------- 256x256 BK=64 4-phase counted-vmcnt GEMM ------------------
// 8 waves (2M x 4N), per-wave 128x64. LDS 128KB: 2 dbuf x (A 32KB + B 32KB).
// Per K-tile: quadrant walk (A0B0)(A0B1)(A1B1)(A1B0); ds_reads 12,4,8,4;
// 16 MFMA per phase. Stage units [Asub0,Bsub0,Bsub1,Asub1](t+1) one per phase;
// per-phase vmcnt(6) (3 units in flight), drain 4/2/0 in last tile.
// Swizzle elem ^= (row&7)<<3 on 128B rows; gl_lds dest linear, source inverse-
// swizzled (both-sides rule). MODE 0: plain C. MODE 1: qkv-split.
template<int MODE, typename OUT>
__global__ __launch_bounds__(512, 2) void gemm256(const u16* __restrict__ A,
                                                  const u16* __restrict__ B,
                                                  OUT* __restrict__ C,
                                                  u16* __restrict__ VT,
                                                  int M, int N, int K){
  __shared__ __align__(16) u16 lA[2][256*64];   // 64 KB
  __shared__ __align__(16) u16 lB[2][256*64];   // 64 KB
  const int tid  = threadIdx.x;
  const int lane = tid & 63;
  const int r16  = lane & 15;
  const int g4   = lane >> 4;
  const int wave = tid >> 6;                 // 0..7
  const int wm = wave >> 2, wn = wave & 3;   // 2M x 4N

  const int nwg = gridDim.x * gridDim.y;
  const int idl = blockIdx.y * gridDim.x + blockIdx.x;
  const int wg  = (idl & 7) * (nwg >> 3) + (idl >> 3);
  const int bx  = wg / gridDim.y, by = wg % gridDim.y;
  const int m0 = by * 256, n0 = bx * 256;

  f32x4 acc[8][4] = {};
  const int nt = K >> 6;

  // stage one unit-part: 2 gl_lds per wave, 8 rows (1024B) each
  auto stA = [&](int b, int t, int sub){
    #pragma unroll
    for (int c=0;c<2;c++){
      const int row0 = wm*128 + sub*64 + wn*16 + c*8;   // wave-uniform
      const int row  = row0 + (lane>>3);
      const int cole = (((lane&7) ^ (row&7)) << 3);
      gl_lds16(&A[(size_t)(m0+row)*K + t*64 + cole], &lA[b][row0*64]);
    }
  };
  auto stB = [&](int b, int t, int sub){
    #pragma unroll
    for (int c=0;c<2;c++){
      const int row0 = wn*64 + sub*32 + wm*16 + c*8;    // wave-uniform
      const int row  = row0 + (lane>>3);
      const int cole = (((lane&7) ^ (row&7)) << 3);
      gl_lds16(&B[(size_t)(n0+row)*K + t*64 + cole], &lB[b][row0*64]);
    }
  };
  auto rdA = [&](short8 (&af)[4][2], int b, int sub){
    #pragma unroll
    for (int i=0;i<4;i++){
      const int R = wm*128 + sub*64 + i*16 + r16;
      #pragma unroll
      for (int ks=0;ks<2;ks++)
        af[i][ks] = *(const short8*)&lA[b][R*64 + ((g4*8 + ks*32) ^ ((R&7)<<3))];
    }
  };
  auto rdB = [&](short8 (&bf)[2][2], int b, int sub){
    #pragma unroll
    for (int j=0;j<2;j++){
      const int R = wn*64 + sub*32 + j*16 + r16;
      #pragma unroll
      for (int ks=0;ks<2;ks++)
        bf[j][ks] = *(const short8*)&lB[b][R*64 + ((g4*8 + ks*32) ^ ((R&7)<<3))];
    }
  };

  // prologue: tile 0's four units, ledger order [Asub0, Bsub0, Bsub1, Asub1]
  stA(0,0,0); stB(0,0,0); stB(0,0,1); stA(0,0,1);

  for (int t = 0; t < nt; ++t){
    const int cb = t & 1, nb = (t + 1) & 1;
    const bool more = (t + 1 < nt);
    short8 af[4][2], bf[2][2];

    // ---- phase 0: quad (A0,B0) — needs Asub0(t), Bsub0(t)
    if (more) stA(nb, t+1, 0);
    if (more) asm volatile("s_waitcnt vmcnt(6)" ::: "memory");
    else      asm volatile("s_waitcnt vmcnt(4)" ::: "memory");
    __builtin_amdgcn_s_barrier();
    asm volatile("" ::: "memory");
    rdA(af, cb, 0); rdB(bf, cb, 0);
    asm volatile("s_waitcnt lgkmcnt(0)" ::: "memory");
    __builtin_amdgcn_sched_barrier(0);
    __builtin_amdgcn_s_setprio(1);
    #pragma unroll
    for (int i=0;i<4;i++)
      #pragma unroll
      for (int j=0;j<2;j++)
        #pragma unroll
        for (int ks=0;ks<2;ks++)
          acc[i][j] = __builtin_amdgcn_mfma_f32_16x16x32_bf16(af[i][ks], bf[j][ks], acc[i][j], 0,0,0);
    __builtin_amdgcn_s_setprio(0);

    // ---- phase 1: quad (A0,B1) — needs Bsub1(t); A-frags reused from regs
    if (more) stB(nb, t+1, 0);
    if (more) asm volatile("s_waitcnt vmcnt(6)" ::: "memory");
    else      asm volatile("s_waitcnt vmcnt(2)" ::: "memory");
    __builtin_amdgcn_s_barrier();
    asm volatile("" ::: "memory");
    rdB(bf, cb, 1);
    asm volatile("s_waitcnt lgkmcnt(0)" ::: "memory");
    __builtin_amdgcn_sched_barrier(0);
    __builtin_amdgcn_s_setprio(1);
    #pragma unroll
    for (int i=0;i<4;i++)
      #pragma unroll
      for (int j=0;j<2;j++)
        #pragma unroll
        for (int ks=0;ks<2;ks++)
          acc[i][2+j] = __builtin_amdgcn_mfma_f32_16x16x32_bf16(af[i][ks], bf[j][ks], acc[i][2+j], 0,0,0);
    __builtin_amdgcn_s_setprio(0);

    // ---- phase 2: quad (A1,B1) — needs Asub1(t); B-frags reused
    if (more) stB(nb, t+1, 1);
    if (more) asm volatile("s_waitcnt vmcnt(6)" ::: "memory");
    else      asm volatile("s_waitcnt vmcnt(0)" ::: "memory");
    __builtin_amdgcn_s_barrier();
    asm volatile("" ::: "memory");
    rdA(af, cb, 1);
    asm volatile("s_waitcnt lgkmcnt(0)" ::: "memory");
    __builtin_amdgcn_sched_barrier(0);
    __builtin_amdgcn_s_setprio(1);
    #pragma unroll
    for (int i=0;i<4;i++)
      #pragma unroll
      for (int j=0;j<2;j++)
        #pragma unroll
        for (int ks=0;ks<2;ks++)
          acc[4+i][2+j] = __builtin_amdgcn_mfma_f32_16x16x32_bf16(af[i][ks], bf[j][ks], acc[4+i][2+j], 0,0,0);
    __builtin_amdgcn_s_setprio(0);

    // ---- phase 3: quad (A1,B0) — re-read Bsub0(t) (already resident)
    if (more) stA(nb, t+1, 1);
    __builtin_amdgcn_s_barrier();
    asm volatile("" ::: "memory");
    rdB(bf, cb, 0);
    asm volatile("s_waitcnt lgkmcnt(0)" ::: "memory");
    __builtin_amdgcn_sched_barrier(0);
    __builtin_amdgcn_s_setprio(1);
    #pragma unroll
    for (int i=0;i<4;i++)
      #pragma unroll
      for (int j=0;j<2;j++)
        #pragma unroll
        for (int ks=0;ks<2;ks++)
          acc[4+i][j] = __builtin_amdgcn_mfma_f32_16x16x32_bf16(af[i][ks], bf[j][ks], acc[4+i][j], 0,0,0);
    __builtin_amdgcn_s_setprio(0);
  }

  if (MODE == 1 && n0 >= 4096){
    #pragma unroll
    for (int i=0;i<8;i++){
      const int m = m0 + wm*128 + i*16 + g4*4;
      const int bb = m >> 11, tt = m & 2047;
      #pragma unroll
      for (int j=0;j<4;j++){
        const int cv = n0 + wn*64 + j*16 + r16 - 4096;
        const int h = cv >> 7, dl = cv & 127;
        ushort4 pack;
        pack.x = f2bf(acc[i][j][0]); pack.y = f2bf(acc[i][j][1]);
        pack.z = f2bf(acc[i][j][2]); pack.w = f2bf(acc[i][j][3]);
        *(ushort4*)&VT[(size_t)((bb<<4) + h)*262144 + (size_t)dl*2048 + tt] = pack;
      }
    }
  } else {
    const int ldc = (MODE == 1) ? 4096 : N;
    #pragma unroll
    for (int i=0;i<8;i++){
      const int row = m0 + wm*128 + i*16 + g4*4;
      #pragma unroll
      for (int j=0;j<4;j++){
        const int col = n0 + wn*64 + j*16 + r16;
        #pragma unroll
        for (int r=0;r<4;r++){
          float v = acc[i][j][r];
          if constexpr (sizeof(OUT)==2) C[(size_t)(row+r)*ldc + col] = (OUT)f2bf(v);
          else                          C[(size_t)(row+r)*ldc + col] = (OUT)v;
        }
      }
    }
  }
}

// ---------------- 128x128 m97-style GEMM (known-good, for out-proj) ---------
__global__ __launch_bounds__(256) void gemm128(const u16* __restrict__ A,
                                               const u16* __restrict__ B,
                                               float* __restrict__ C,
                                               int M, int N, int K){
  __shared__ __align__(16) u16 lA[2][128*32];
  __shared__ __align__(16) u16 lB[2][128*32];
  const int tid  = threadIdx.x;
  const int lane = tid & 63;
  const int r16  = lane & 15;
  const int g4   = lane >> 4;
  const int wave = tid >> 6;
  const int wr = (wave >> 1) * 64, wc = (wave & 1) * 64;

  const int nwg = gridDim.x * gridDim.y;
  const int idl = blockIdx.y * gridDim.x + blockIdx.x;
  const int wg  = (idl & 7) * (nwg >> 3) + (idl >> 3);
  const int bx  = wg / gridDim.y, by = wg % gridDim.y;
  const int m0 = by * 128, n0 = bx * 128;

  const int srow = tid >> 2;
  const int scol = (tid & 3) << 3;

  f32x4 acc[4][4] = {};
  const int nk = K >> 5;
  int buf = 0;

  gl_lds16(&A[(size_t)(m0 + srow)*K + scol],      &lA[0][srow*32 + scol]);
  gl_lds16(&A[(size_t)(m0 + 64 + srow)*K + scol], &lA[0][(64+srow)*32 + scol]);
  gl_lds16(&B[(size_t)(n0 + srow)*K + scol],      &lB[0][srow*32 + scol]);
  gl_lds16(&B[(size_t)(n0 + 64 + srow)*K + scol], &lB[0][(64+srow)*32 + scol]);

  for (int kt = 0; kt < nk; ++kt){
    __syncthreads();
    if (kt + 1 < nk){
      const int k0 = (kt + 1) << 5;
      gl_lds16(&A[(size_t)(m0 + srow)*K + k0 + scol],      &lA[buf^1][srow*32 + scol]);
      gl_lds16(&A[(size_t)(m0 + 64 + srow)*K + k0 + scol], &lA[buf^1][(64+srow)*32 + scol]);
      gl_lds16(&B[(size_t)(n0 + srow)*K + k0 + scol],      &lB[buf^1][srow*32 + scol]);
      gl_lds16(&B[(size_t)(n0 + 64 + srow)*K + k0 + scol], &lB[buf^1][(64+srow)*32 + scol]);
    }
    short8 af[4], bfv[4];
    #pragma unroll
    for (int i=0;i<4;i++)
      af[i] = *(const short8*)&lA[buf][(wr + i*16 + r16)*32 + g4*8];
    #pragma unroll
    for (int j=0;j<4;j++)
      bfv[j] = *(const short8*)&lB[buf][(wc + j*16 + r16)*32 + g4*8];
    #pragma unroll
    for (int i=0;i<4;i++)
      #pragma unroll
      for (int j=0;j<4;j++)
        acc[i][j] = __builtin_amdgcn_mfma_f32_16x16x32_bf16(af[i], bfv[j], acc[i][j], 0,0,0);
    buf ^= 1;
  }

  #pragma unroll
  for (int i=0;i<4;i++){
    const int row = m0 + wr + i*16 + g4*4;
    #pragma unroll
    for (int j=0;j<4;j++){
      const int col = n0 + wc + j*16 + r16;
      #pragma unroll
      for (int r=0;r<4;r++)
        C[(size_t)(row+r)*N + col] = acc[i][j][r];
    }
  }
}

// ---------------- Flash attention (round-5, unchanged) ----------------------
__global__ __launch_bounds__(256) void attn_kernel(const u16* __restrict__ qk,
                                                   const u16* __restrict__ vt,
                                                   u16* __restrict__ y){
  __shared__ __align__(16) u16 Kl[2][64*128];
  __shared__ __align__(16) u16 Vl[2][128*64];
  __shared__ __align__(16) u16 Pl[4][32*64];

  const int tid = threadIdx.x, lane = tid & 63, wave = tid >> 6;
  const int r16 = lane & 15, g4 = lane >> 4;

  const int id = blockIdx.x;
  const int xk = id & 7,  kk = id >> 3;
  const int bh = 4*xk + (kk & 3);
  const int v5 = kk >> 2;
  const int qt = (v5 < 8) ? v5 : (23 - v5);

  const int b = bh >> 4, h = bh & 15;
  const int qcol = h*128, kcol = 2048 + h*128;
  const u16* vhead = vt + (size_t)bh * 262144;
  const float scale = 0.08838834764831845f;

  short8 qf[2][4];
  #pragma unroll
  for (int i=0;i<2;i++){
    const u16* qp = qk + (size_t)(b*T_SEQ + qt*128 + wave*32 + i*16 + r16)*4096 + qcol;
    #pragma unroll
    for (int c=0;c<4;c++) qf[i][c] = *(const short8*)&qp[g4*8 + c*32];
  }

  float mrow[2][4], lrow[2][4];
  #pragma unroll
  for (int i=0;i<2;i++)
    #pragma unroll
    for (int r=0;r<4;r++){ mrow[i][r] = -1e30f; lrow[i][r] = 0.f; }
  f32x4 o[2][8] = {};

  const int nt = 2*qt + 2;

  auto stage = [&](int sbuf, int t){
    const size_t kbase = (size_t)(b*T_SEQ + t*64)*4096 + kcol;
    #pragma unroll
    for (int c=0;c<4;c++){
      const int row0 = wave*16 + c*4;
      const int row  = row0 + g4;
      gl_lds16(&qk[kbase + (size_t)row*4096 + ((r16*8) ^ ((row&7)<<3))],
               &Kl[sbuf][row0*128]);
    }
    const int t0 = t*64;
    #pragma unroll
    for (int c=0;c<4;c++){
      const int idx = wave*4 + c;
      const int d   = idx*8 + (lane>>3);
      const int j8  = (lane&7)*8;
      gl_lds16(&vhead[(size_t)d*2048 + t0 + (j8 ^ ((d&7)<<3))],
               &Vl[sbuf][idx*512]);
    }
  };

  stage(0, 0);
  int cur = 0;

  for (int t = 0; t < nt; ++t){
    __syncthreads();
    if (t + 1 < nt) stage(cur^1, t+1);

    float smat[2][4][4];
    #pragma unroll
    for (int cc=0;cc<4;cc++){
      const int krow = cc*16 + r16;
      const int sw = (krow & 7) << 3;
      short8 kf[4];
      #pragma unroll
      for (int dc=0;dc<4;dc++)
        kf[dc] = *(const short8*)&Kl[cur][krow*128 + ((g4*8 + dc*32) ^ sw)];
      #pragma unroll
      for (int i=0;i<2;i++){
        f32x4 sv = {0.f,0.f,0.f,0.f};
        #pragma unroll
        for (int dc=0;dc<4;dc++)
          sv = __builtin_amdgcn_mfma_f32_16x16x32_bf16(qf[i][dc], kf[dc], sv, 0,0,0);
        #pragma unroll
        for (int rr=0;rr<4;rr++) smat[i][cc][rr] = sv[rr] * scale;
      }
    }
    if (t >= 2*qt){
      #pragma unroll
      for (int cc=0;cc<4;cc++){
        const int kvl = (t - 2*qt)*64 + cc*16 + r16;
        #pragma unroll
        for (int i=0;i<2;i++)
          #pragma unroll
          for (int rr=0;rr<4;rr++){
            const int qi = wave*32 + i*16 + g4*4 + rr;
            if (kvl > qi) smat[i][cc][rr] = -1e30f;
          }
      }
    }

    float corr[2][4];
    #pragma unroll
    for (int i=0;i<2;i++)
      #pragma unroll
      for (int rr=0;rr<4;rr++){
        float pm = fmaxf(fmaxf(smat[i][0][rr], smat[i][1][rr]),
                         fmaxf(smat[i][2][rr], smat[i][3][rr]));
        #pragma unroll
        for (int off=1; off<16; off<<=1) pm = fmaxf(pm, __shfl_xor(pm, off, 64));
        const float mnew = fmaxf(mrow[i][rr], pm);
        corr[i][rr] = __expf(mrow[i][rr] - mnew);
        float s0 = 0.f;
        #pragma unroll
        for (int cc=0;cc<4;cc++){
          const float p = __expf(smat[i][cc][rr] - mnew);
          smat[i][cc][rr] = p;
          s0 += p;
        }
        #pragma unroll
        for (int off=1; off<16; off<<=1) s0 += __shfl_xor(s0, off, 64);
        lrow[i][rr] = lrow[i][rr]*corr[i][rr] + s0;
        mrow[i][rr] = mnew;
      }
    #pragma unroll
    for (int i=0;i<2;i++)
      #pragma unroll
      for (int n=0;n<8;n++)
        #pragma unroll
        for (int rr=0;rr<4;rr++)
          o[i][n][rr] *= corr[i][rr];

    #pragma unroll
    for (int i=0;i<2;i++)
      #pragma unroll
      for (int cc=0;cc<4;cc++)
        #pragma unroll
        for (int rr=0;rr<4;rr++){
          const int qr = i*16 + g4*4 + rr;
          Pl[wave][qr*64 + ((cc*16 + r16) ^ ((qr&7)<<3))] = f2bf(smat[i][cc][rr]);
        }
    asm volatile("s_waitcnt lgkmcnt(0)" ::: "memory");

    short8 pf[2][2];
    #pragma unroll
    for (int i=0;i<2;i++){
      const int qr = i*16 + r16;
      const int sw = (qr & 7) << 3;
      pf[i][0] = *(const short8*)&Pl[wave][qr*64 + ((g4*8)      ^ sw)];
      pf[i][1] = *(const short8*)&Pl[wave][qr*64 + ((g4*8 + 32) ^ sw)];
    }
    #pragma unroll
    for (int n=0;n<8;n++){
      const int vr = n*16 + r16;
      const int sw = (vr & 7) << 3;
      short8 vf0 = *(const short8*)&Vl[cur][vr*64 + ((g4*8)      ^ sw)];
      short8 vf1 = *(const short8*)&Vl[cur][vr*64 + ((g4*8 + 32) ^ sw)];
      #pragma unroll
      for (int i=0;i<2;i++){
        o[i][n] = __builtin_amdgcn_mfma_f32_16x16x32_bf16(pf[i][0], vf0, o[i][n], 0,0,0);
        o[i][n] = __builtin_amdgcn_mfma_f32_16x16x32_bf16(pf[i][1], vf1, o[i][n], 0,0,0);
      }
    }
    cur ^= 1;
  }

  #pragma unroll
  for (int i=0;i<2;i++){
    const size_t yr0 = (size_t)(b*T_SEQ + qt*128 + wave*32 + i*16 + g4*4) * C_DIM + h*128;
    #pragma unroll
    for (int n=0;n<8;n++)
      #pragma unroll
      for (int rr=0;rr<4;rr++){
        const float v = o[i][n][rr] / lrow[i][rr];
        y[yr0 + (size_t)rr*C_DIM + n*16 + r16] = f2bf(v);
      }
  }
}

extern "C" void kernel_launch(void* const* d_in, const int* in_sizes, int n_in,
                              void* d_out, int out_size, void* d_ws, size_t ws_size,
                              hipStream_t stream){
  const float* x  = (const float*)d_in[0];
  const float* wa = (const float*)d_in[1];
  const float* wp = (const float*)d_in[2];
  float* out = (float*)d_out;

  u16* ws  = (u16*)d_ws;
  u16* xb  = ws;                 //  8,388,608 elems (x bf16) — reused as yb later
  u16* wab = xb  + 8388608;      // 12,582,912 elems (w_attn bf16)
  u16* wpb = wab + 12582912;     //  4,194,304 elems (w_proj bf16)
  u16* qk  = wpb + 4194304;      // 16,777,216 elems ([4096][4096] Q|K)
  u16* vt  = qk  + 16777216;     //  8,388,608 elems ([32][128][2048] V^T)
  u16* yb  = xb;                 // alias: x dead after GEMM1

  hipLaunchKernelGGL(cvt_kernel, dim3(1024), dim3(256), 0, stream, x,  xb,  8388608/4);
  hipLaunchKernelGGL(cvt_kernel, dim3(1024), dim3(256), 0, stream, wa, wab, 12582912/4);
  hipLaunchKernelGGL(cvt_kernel, dim3(1024), dim3(256), 0, stream, wp, wpb, 4194304/4);

  // qkv projection: grid 24 n-tiles(256) x 16 m-tiles(256) = 384 blocks
  hipLaunchKernelGGL((gemm256<1,u16>), dim3(24,16), dim3(512), 0, stream,
                     xb, wab, qk, vt, 4096, 6144, 2048);
  hipLaunchKernelGGL(attn_kernel,      dim3(512),  dim3(256), 0, stream,
                     qk, vt, yb);
  // out projection: 128x128 tiles, grid 16 x 32 = 512 blocks
  hipLaunchKernelGGL(gemm128,          dim3(16,32), dim3(256), 0, stream,
                     yb, wpb, out, 4096, 2048, 2048);
}

// Round 9
// 322.952 us; speedup vs baseline: 1.0822x; 1.0822x over previous
//
#include <hip/hip_runtime.h>

typedef __attribute__((ext_vector_type(8))) short short8;
typedef __attribute__((ext_vector_type(4))) float f32x4;
typedef unsigned short u16;

#define T_SEQ 2048
#define C_DIM 2048

static __device__ __forceinline__ u16 f2bf(float f){
  unsigned u = __float_as_uint(f);
  u = (u + 0x7fffu + ((u >> 16) & 1u)) >> 16;
  return (u16)u;
}

__global__ void cvt_kernel(const float* __restrict__ in, u16* __restrict__ out, int n4){
  int idx = blockIdx.x * blockDim.x + threadIdx.x;
  int stride = gridDim.x * blockDim.x;
  for (int i = idx; i < n4; i += stride){
    float4 v = ((const float4*)in)[i];
    ushort4 o;
    o.x = f2bf(v.x); o.y = f2bf(v.y); o.z = f2bf(v.z); o.w = f2bf(v.w);
    ((ushort4*)out)[i] = o;
  }
}

__device__ __forceinline__ void gl_lds16(const void* g, void* l){
  __builtin_amdgcn_global_load_lds(
      (const __attribute__((address_space(1))) unsigned int*)g,
      (__attribute__((address_space(3))) unsigned int*)l,
      16, 0, 0);
}

// ---------------- 256x256 BK=64 4-phase counted-vmcnt GEMM ------------------
// 8 waves (2M x 4N), per-wave 128x64, 2dbuf x (A 32KB + B 32KB) = 128KB LDS.
// Phase = {ds_reads(this phase); stage 1 unit(t+1); [vmcnt]; barrier;
//          lgkmcnt(0); 16 MFMA; barrier}. Reads issue BEFORE the barrier so
// LDS completion overlaps barrier arrival (m201 structure). vmcnt ledger
// (guarantee-one-phase-early, FIFO): stage order [A0,B0,B1,A1](t+1) at
// P0..P3 -> vmcnt(4)@P0 covers B1(t), vmcnt(4)@P1 covers A1(t), none@P2,
// vmcnt(4)@P3 covers A0,B0(t+1). Last tile: 2/0/none/none. B0 frags are
// register-carried P0->P3. Swizzle elem ^= (row&7)<<3, inverse-swizzled
// global source (both-sides rule). MODE 0: plain C. MODE 1: qkv-split.
template<int MODE, typename OUT>
__global__ __launch_bounds__(512, 2) void gemm256(const u16* __restrict__ A,
                                                  const u16* __restrict__ B,
                                                  OUT* __restrict__ C,
                                                  u16* __restrict__ VT,
                                                  int M, int N, int K){
  __shared__ __align__(16) u16 lA[2][256*64];   // 64 KB
  __shared__ __align__(16) u16 lB[2][256*64];   // 64 KB
  const int tid  = threadIdx.x;
  const int lane = tid & 63;
  const int r16  = lane & 15;
  const int g4   = lane >> 4;
  const int wave = tid >> 6;                 // 0..7
  const int wm = wave >> 2, wn = wave & 3;   // 2M x 4N

  const int nwg = gridDim.x * gridDim.y;
  const int idl = blockIdx.y * gridDim.x + blockIdx.x;
  const int wg  = (idl & 7) * (nwg >> 3) + (idl >> 3);
  const int bx  = wg / gridDim.y, by = wg % gridDim.y;
  const int m0 = by * 256, n0 = bx * 256;

  f32x4 acc[8][4] = {};
  const int nt = K >> 6;

  auto stA = [&](int b, int t, int sub){
    #pragma unroll
    for (int c=0;c<2;c++){
      const int row0 = wm*128 + sub*64 + wn*16 + c*8;   // wave-uniform
      const int row  = row0 + (lane>>3);
      const int cole = (((lane&7) ^ (row&7)) << 3);
      gl_lds16(&A[(size_t)(m0+row)*K + t*64 + cole], &lA[b][row0*64]);
    }
  };
  auto stB = [&](int b, int t, int sub){
    #pragma unroll
    for (int c=0;c<2;c++){
      const int row0 = wn*64 + sub*32 + wm*16 + c*8;    // wave-uniform
      const int row  = row0 + (lane>>3);
      const int cole = (((lane&7) ^ (row&7)) << 3);
      gl_lds16(&B[(size_t)(n0+row)*K + t*64 + cole], &lB[b][row0*64]);
    }
  };
  auto rdA = [&](short8 (&af)[4][2], int b, int sub){
    #pragma unroll
    for (int i=0;i<4;i++){
      const int R = wm*128 + sub*64 + i*16 + r16;
      #pragma unroll
      for (int ks=0;ks<2;ks++)
        af[i][ks] = *(const short8*)&lA[b][R*64 + ((g4*8 + ks*32) ^ ((R&7)<<3))];
    }
  };
  auto rdB = [&](short8 (&bf)[2][2], int b, int sub){
    #pragma unroll
    for (int j=0;j<2;j++){
      const int R = wn*64 + sub*32 + j*16 + r16;
      #pragma unroll
      for (int ks=0;ks<2;ks++)
        bf[j][ks] = *(const short8*)&lB[b][R*64 + ((g4*8 + ks*32) ^ ((R&7)<<3))];
    }
  };

  // prologue: tile 0's units in ledger order; guarantee A0,B0 before P0 reads
  stA(0,0,0); stB(0,0,0); stB(0,0,1); stA(0,0,1);
  asm volatile("s_waitcnt vmcnt(4)" ::: "memory");
  __builtin_amdgcn_s_barrier();
  asm volatile("" ::: "memory");

  for (int t = 0; t < nt; ++t){
    const int cb = t & 1, nb = cb ^ 1;
    const bool more = (t + 1 < nt);
    short8 af[4][2], bf[2][2], bf0[2][2];

    // ---- P0: (A0,B0). reads A0,B0; stage A0(t+1); vmcnt covers B1(t)
    rdA(af, cb, 0); rdB(bf0, cb, 0);
    if (more){ stA(nb, t+1, 0); asm volatile("s_waitcnt vmcnt(4)" ::: "memory"); }
    else     {                  asm volatile("s_waitcnt vmcnt(2)" ::: "memory"); }
    __builtin_amdgcn_s_barrier();
    asm volatile("s_waitcnt lgkmcnt(0)" ::: "memory");
    __builtin_amdgcn_sched_barrier(0);
    __builtin_amdgcn_s_setprio(1);
    #pragma unroll
    for (int i=0;i<4;i++)
      #pragma unroll
      for (int j=0;j<2;j++)
        #pragma unroll
        for (int ks=0;ks<2;ks++)
          acc[i][j] = __builtin_amdgcn_mfma_f32_16x16x32_bf16(af[i][ks], bf0[j][ks], acc[i][j], 0,0,0);
    __builtin_amdgcn_s_setprio(0);
    __builtin_amdgcn_s_barrier();
    asm volatile("" ::: "memory");

    // ---- P1: (A0,B1). reads B1; stage B0(t+1); vmcnt covers A1(t)
    rdB(bf, cb, 1);
    if (more){ stB(nb, t+1, 0); asm volatile("s_waitcnt vmcnt(4)" ::: "memory"); }
    else     {                  asm volatile("s_waitcnt vmcnt(0)" ::: "memory"); }
    __builtin_amdgcn_s_barrier();
    asm volatile("s_waitcnt lgkmcnt(0)" ::: "memory");
    __builtin_amdgcn_sched_barrier(0);
    __builtin_amdgcn_s_setprio(1);
    #pragma unroll
    for (int i=0;i<4;i++)
      #pragma unroll
      for (int j=0;j<2;j++)
        #pragma unroll
        for (int ks=0;ks<2;ks++)
          acc[i][2+j] = __builtin_amdgcn_mfma_f32_16x16x32_bf16(af[i][ks], bf[j][ks], acc[i][2+j], 0,0,0);
    __builtin_amdgcn_s_setprio(0);
    __builtin_amdgcn_s_barrier();
    asm volatile("" ::: "memory");

    // ---- P2: (A1,B1). reads A1; stage B1(t+1); no vmcnt
    rdA(af, cb, 1);
    if (more) stB(nb, t+1, 1);
    __builtin_amdgcn_s_barrier();
    asm volatile("s_waitcnt lgkmcnt(0)" ::: "memory");
    __builtin_amdgcn_sched_barrier(0);
    __builtin_amdgcn_s_setprio(1);
    #pragma unroll
    for (int i=0;i<4;i++)
      #pragma unroll
      for (int j=0;j<2;j++)
        #pragma unroll
        for (int ks=0;ks<2;ks++)
          acc[4+i][2+j] = __builtin_amdgcn_mfma_f32_16x16x32_bf16(af[i][ks], bf[j][ks], acc[4+i][2+j], 0,0,0);
    __builtin_amdgcn_s_setprio(0);
    __builtin_amdgcn_s_barrier();
    asm volatile("" ::: "memory");

    // ---- P3: (A1,B0) from regs. stage A1(t+1); vmcnt covers A0,B0(t+1)
    if (more){ stA(nb, t+1, 1); asm volatile("s_waitcnt vmcnt(4)" ::: "memory"); }
    __builtin_amdgcn_s_barrier();
    __builtin_amdgcn_s_setprio(1);
    #pragma unroll
    for (int i=0;i<4;i++)
      #pragma unroll
      for (int j=0;j<2;j++)
        #pragma unroll
        for (int ks=0;ks<2;ks++)
          acc[4+i][j] = __builtin_amdgcn_mfma_f32_16x16x32_bf16(af[i][ks], bf0[j][ks], acc[4+i][j], 0,0,0);
    __builtin_amdgcn_s_setprio(0);
    __builtin_amdgcn_s_barrier();
    asm volatile("" ::: "memory");
  }

  if (MODE == 1 && n0 >= 4096){
    #pragma unroll
    for (int i=0;i<8;i++){
      const int m = m0 + wm*128 + i*16 + g4*4;
      const int bb = m >> 11, tt = m & 2047;
      #pragma unroll
      for (int j=0;j<4;j++){
        const int cv = n0 + wn*64 + j*16 + r16 - 4096;
        const int h = cv >> 7, dl = cv & 127;
        ushort4 pack;
        pack.x = f2bf(acc[i][j][0]); pack.y = f2bf(acc[i][j][1]);
        pack.z = f2bf(acc[i][j][2]); pack.w = f2bf(acc[i][j][3]);
        *(ushort4*)&VT[(size_t)((bb<<4) + h)*262144 + (size_t)dl*2048 + tt] = pack;
      }
    }
  } else {
    const int ldc = (MODE == 1) ? 4096 : N;
    #pragma unroll
    for (int i=0;i<8;i++){
      const int row = m0 + wm*128 + i*16 + g4*4;
      #pragma unroll
      for (int j=0;j<4;j++){
        const int col = n0 + wn*64 + j*16 + r16;
        #pragma unroll
        for (int r=0;r<4;r++){
          float v = acc[i][j][r];
          if constexpr (sizeof(OUT)==2) C[(size_t)(row+r)*ldc + col] = (OUT)f2bf(v);
          else                          C[(size_t)(row+r)*ldc + col] = (OUT)v;
        }
      }
    }
  }
}

// ---------------- 128x128 m97-style GEMM (known-good, for out-proj) ---------
__global__ __launch_bounds__(256) void gemm128(const u16* __restrict__ A,
                                               const u16* __restrict__ B,
                                               float* __restrict__ C,
                                               int M, int N, int K){
  __shared__ __align__(16) u16 lA[2][128*32];
  __shared__ __align__(16) u16 lB[2][128*32];
  const int tid  = threadIdx.x;
  const int lane = tid & 63;
  const int r16  = lane & 15;
  const int g4   = lane >> 4;
  const int wave = tid >> 6;
  const int wr = (wave >> 1) * 64, wc = (wave & 1) * 64;

  const int nwg = gridDim.x * gridDim.y;
  const int idl = blockIdx.y * gridDim.x + blockIdx.x;
  const int wg  = (idl & 7) * (nwg >> 3) + (idl >> 3);
  const int bx  = wg / gridDim.y, by = wg % gridDim.y;
  const int m0 = by * 128, n0 = bx * 128;

  const int srow = tid >> 2;
  const int scol = (tid & 3) << 3;

  f32x4 acc[4][4] = {};
  const int nk = K >> 5;
  int buf = 0;

  gl_lds16(&A[(size_t)(m0 + srow)*K + scol],      &lA[0][srow*32 + scol]);
  gl_lds16(&A[(size_t)(m0 + 64 + srow)*K + scol], &lA[0][(64+srow)*32 + scol]);
  gl_lds16(&B[(size_t)(n0 + srow)*K + scol],      &lB[0][srow*32 + scol]);
  gl_lds16(&B[(size_t)(n0 + 64 + srow)*K + scol], &lB[0][(64+srow)*32 + scol]);

  for (int kt = 0; kt < nk; ++kt){
    __syncthreads();
    if (kt + 1 < nk){
      const int k0 = (kt + 1) << 5;
      gl_lds16(&A[(size_t)(m0 + srow)*K + k0 + scol],      &lA[buf^1][srow*32 + scol]);
      gl_lds16(&A[(size_t)(m0 + 64 + srow)*K + k0 + scol], &lA[buf^1][(64+srow)*32 + scol]);
      gl_lds16(&B[(size_t)(n0 + srow)*K + k0 + scol],      &lB[buf^1][srow*32 + scol]);
      gl_lds16(&B[(size_t)(n0 + 64 + srow)*K + k0 + scol], &lB[buf^1][(64+srow)*32 + scol]);
    }
    short8 af[4], bfv[4];
    #pragma unroll
    for (int i=0;i<4;i++)
      af[i] = *(const short8*)&lA[buf][(wr + i*16 + r16)*32 + g4*8];
    #pragma unroll
    for (int j=0;j<4;j++)
      bfv[j] = *(const short8*)&lB[buf][(wc + j*16 + r16)*32 + g4*8];
    #pragma unroll
    for (int i=0;i<4;i++)
      #pragma unroll
      for (int j=0;j<4;j++)
        acc[i][j] = __builtin_amdgcn_mfma_f32_16x16x32_bf16(af[i], bfv[j], acc[i][j], 0,0,0);
    buf ^= 1;
  }

  #pragma unroll
  for (int i=0;i<4;i++){
    const int row = m0 + wr + i*16 + g4*4;
    #pragma unroll
    for (int j=0;j<4;j++){
      const int col = n0 + wc + j*16 + r16;
      #pragma unroll
      for (int r=0;r<4;r++)
        C[(size_t)(row+r)*N + col] = acc[i][j][r];
    }
  }
}

// ---------------- Flash attention (round-5, unchanged) ----------------------
__global__ __launch_bounds__(256) void attn_kernel(const u16* __restrict__ qk,
                                                   const u16* __restrict__ vt,
                                                   u16* __restrict__ y){
  __shared__ __align__(16) u16 Kl[2][64*128];
  __shared__ __align__(16) u16 Vl[2][128*64];
  __shared__ __align__(16) u16 Pl[4][32*64];

  const int tid = threadIdx.x, lane = tid & 63, wave = tid >> 6;
  const int r16 = lane & 15, g4 = lane >> 4;

  const int id = blockIdx.x;
  const int xk = id & 7,  kk = id >> 3;
  const int bh = 4*xk + (kk & 3);
  const int v5 = kk >> 2;
  const int qt = (v5 < 8) ? v5 : (23 - v5);

  const int b = bh >> 4, h = bh & 15;
  const int qcol = h*128, kcol = 2048 + h*128;
  const u16* vhead = vt + (size_t)bh * 262144;
  const float scale = 0.08838834764831845f;

  short8 qf[2][4];
  #pragma unroll
  for (int i=0;i<2;i++){
    const u16* qp = qk + (size_t)(b*T_SEQ + qt*128 + wave*32 + i*16 + r16)*4096 + qcol;
    #pragma unroll
    for (int c=0;c<4;c++) qf[i][c] = *(const short8*)&qp[g4*8 + c*32];
  }

  float mrow[2][4], lrow[2][4];
  #pragma unroll
  for (int i=0;i<2;i++)
    #pragma unroll
    for (int r=0;r<4;r++){ mrow[i][r] = -1e30f; lrow[i][r] = 0.f; }
  f32x4 o[2][8] = {};

  const int nt = 2*qt + 2;

  auto stage = [&](int sbuf, int t){
    const size_t kbase = (size_t)(b*T_SEQ + t*64)*4096 + kcol;
    #pragma unroll
    for (int c=0;c<4;c++){
      const int row0 = wave*16 + c*4;
      const int row  = row0 + g4;
      gl_lds16(&qk[kbase + (size_t)row*4096 + ((r16*8) ^ ((row&7)<<3))],
               &Kl[sbuf][row0*128]);
    }
    const int t0 = t*64;
    #pragma unroll
    for (int c=0;c<4;c++){
      const int idx = wave*4 + c;
      const int d   = idx*8 + (lane>>3);
      const int j8  = (lane&7)*8;
      gl_lds16(&vhead[(size_t)d*2048 + t0 + (j8 ^ ((d&7)<<3))],
               &Vl[sbuf][idx*512]);
    }
  };

  stage(0, 0);
  int cur = 0;

  for (int t = 0; t < nt; ++t){
    __syncthreads();
    if (t + 1 < nt) stage(cur^1, t+1);

    float smat[2][4][4];
    #pragma unroll
    for (int cc=0;cc<4;cc++){
      const int krow = cc*16 + r16;
      const int sw = (krow & 7) << 3;
      short8 kf[4];
      #pragma unroll
      for (int dc=0;dc<4;dc++)
        kf[dc] = *(const short8*)&Kl[cur][krow*128 + ((g4*8 + dc*32) ^ sw)];
      #pragma unroll
      for (int i=0;i<2;i++){
        f32x4 sv = {0.f,0.f,0.f,0.f};
        #pragma unroll
        for (int dc=0;dc<4;dc++)
          sv = __builtin_amdgcn_mfma_f32_16x16x32_bf16(qf[i][dc], kf[dc], sv, 0,0,0);
        #pragma unroll
        for (int rr=0;rr<4;rr++) smat[i][cc][rr] = sv[rr] * scale;
      }
    }
    if (t >= 2*qt){
      #pragma unroll
      for (int cc=0;cc<4;cc++){
        const int kvl = (t - 2*qt)*64 + cc*16 + r16;
        #pragma unroll
        for (int i=0;i<2;i++)
          #pragma unroll
          for (int rr=0;rr<4;rr++){
            const int qi = wave*32 + i*16 + g4*4 + rr;
            if (kvl > qi) smat[i][cc][rr] = -1e30f;
          }
      }
    }

    float corr[2][4];
    #pragma unroll
    for (int i=0;i<2;i++)
      #pragma unroll
      for (int rr=0;rr<4;rr++){
        float pm = fmaxf(fmaxf(smat[i][0][rr], smat[i][1][rr]),
                         fmaxf(smat[i][2][rr], smat[i][3][rr]));
        #pragma unroll
        for (int off=1; off<16; off<<=1) pm = fmaxf(pm, __shfl_xor(pm, off, 64));
        const float mnew = fmaxf(mrow[i][rr], pm);
        corr[i][rr] = __expf(mrow[i][rr] - mnew);
        float s0 = 0.f;
        #pragma unroll
        for (int cc=0;cc<4;cc++){
          const float p = __expf(smat[i][cc][rr] - mnew);
          smat[i][cc][rr] = p;
          s0 += p;
        }
        #pragma unroll
        for (int off=1; off<16; off<<=1) s0 += __shfl_xor(s0, off, 64);
        lrow[i][rr] = lrow[i][rr]*corr[i][rr] + s0;
        mrow[i][rr] = mnew;
      }
    #pragma unroll
    for (int i=0;i<2;i++)
      #pragma unroll
      for (int n=0;n<8;n++)
        #pragma unroll
        for (int rr=0;rr<4;rr++)
          o[i][n][rr] *= corr[i][rr];

    #pragma unroll
    for (int i=0;i<2;i++)
      #pragma unroll
      for (int cc=0;cc<4;cc++)
        #pragma unroll
        for (int rr=0;rr<4;rr++){
          const int qr = i*16 + g4*4 + rr;
          Pl[wave][qr*64 + ((cc*16 + r16) ^ ((qr&7)<<3))] = f2bf(smat[i][cc][rr]);
        }
    asm volatile("s_waitcnt lgkmcnt(0)" ::: "memory");

    short8 pf[2][2];
    #pragma unroll
    for (int i=0;i<2;i++){
      const int qr = i*16 + r16;
      const int sw = (qr & 7) << 3;
      pf[i][0] = *(const short8*)&Pl[wave][qr*64 + ((g4*8)      ^ sw)];
      pf[i][1] = *(const short8*)&Pl[wave][qr*64 + ((g4*8 + 32) ^ sw)];
    }
    #pragma unroll
    for (int n=0;n<8;n++){
      const int vr = n*16 + r16;
      const int sw = (vr & 7) << 3;
      short8 vf0 = *(const short8*)&Vl[cur][vr*64 + ((g4*8)      ^ sw)];
      short8 vf1 = *(const short8*)&Vl[cur][vr*64 + ((g4*8 + 32) ^ sw)];
      #pragma unroll
      for (int i=0;i<2;i++){
        o[i][n] = __builtin_amdgcn_mfma_f32_16x16x32_bf16(pf[i][0], vf0, o[i][n], 0,0,0);
        o[i][n] = __builtin_amdgcn_mfma_f32_16x16x32_bf16(pf[i][1], vf1, o[i][n], 0,0,0);
      }
    }
    cur ^= 1;
  }

  #pragma unroll
  for (int i=0;i<2;i++){
    const size_t yr0 = (size_t)(b*T_SEQ + qt*128 + wave*32 + i*16 + g4*4) * C_DIM + h*128;
    #pragma unroll
    for (int n=0;n<8;n++)
      #pragma unroll
      for (int rr=0;rr<4;rr++){
        const float v = o[i][n][rr] / lrow[i][rr];
        y[yr0 + (size_t)rr*C_DIM + n*16 + r16] = f2bf(v);
      }
  }
}

extern "C" void kernel_launch(void* const* d_in, const int* in_sizes, int n_in,
                              void* d_out, int out_size, void* d_ws, size_t ws_size,
                              hipStream_t stream){
  const float* x  = (const float*)d_in[0];
  const float* wa = (const float*)d_in[1];
  const float* wp = (const float*)d_in[2];
  float* out = (float*)d_out;

  u16* ws  = (u16*)d_ws;
  u16* xb  = ws;                 //  8,388,608 elems (x bf16) — reused as yb later
  u16* wab = xb  + 8388608;      // 12,582,912 elems (w_attn bf16)
  u16* wpb = wab + 12582912;     //  4,194,304 elems (w_proj bf16)
  u16* qk  = wpb + 4194304;      // 16,777,216 elems ([4096][4096] Q|K)
  u16* vt  = qk  + 16777216;     //  8,388,608 elems ([32][128][2048] V^T)
  u16* yb  = xb;                 // alias: x dead after GEMM1

  hipLaunchKernelGGL(cvt_kernel, dim3(1024), dim3(256), 0, stream, x,  xb,  8388608/4);
  hipLaunchKernelGGL(cvt_kernel, dim3(1024), dim3(256), 0, stream, wa, wab, 12582912/4);
  hipLaunchKernelGGL(cvt_kernel, dim3(1024), dim3(256), 0, stream, wp, wpb, 4194304/4);

  // qkv projection: grid 24 n-tiles(256) x 16 m-tiles(256) = 384 blocks
  hipLaunchKernelGGL((gemm256<1,u16>), dim3(24,16), dim3(512), 0, stream,
                     xb, wab, qk, vt, 4096, 6144, 2048);
  hipLaunchKernelGGL(attn_kernel,      dim3(512),  dim3(256), 0, stream,
                     qk, vt, yb);
  // out projection: 128x128 tiles, grid 16 x 32 = 512 blocks
  hipLaunchKernelGGL(gemm128,          dim3(16,32), dim3(256), 0, stream,
                     yb, wpb, out, 4096, 2048, 2048);
}

// Round 12
// 306.144 us; speedup vs baseline: 1.1416x; 1.0549x over previous
//
#include <hip/hip_runtime.h>

typedef __attribute__((ext_vector_type(8))) short short8;
typedef __attribute__((ext_vector_type(4))) float f32x4;
typedef unsigned short u16;

#define T_SEQ 2048
#define C_DIM 2048

static __device__ __forceinline__ u16 f2bf(float f){
  unsigned u = __float_as_uint(f);
  u = (u + 0x7fffu + ((u >> 16) & 1u)) >> 16;
  return (u16)u;
}

// merged f32->bf16 convert for x (2097152 float4), w_attn (3145728), w_proj (1048576)
__global__ void cvt3_kernel(const float* __restrict__ x,
                            const float* __restrict__ wa,
                            const float* __restrict__ wp,
                            u16* __restrict__ xb, u16* __restrict__ wab,
                            u16* __restrict__ wpb){
  int idx = blockIdx.x * blockDim.x + threadIdx.x;
  int stride = gridDim.x * blockDim.x;
  for (int i = idx; i < 6291456; i += stride){
    const float* src; u16* dst; int j;
    if (i < 2097152){ src = x;  dst = xb;  j = i; }
    else if (i < 5242880){ src = wa; dst = wab; j = i - 2097152; }
    else { src = wp; dst = wpb; j = i - 5242880; }
    float4 v = ((const float4*)src)[j];
    ushort4 o;
    o.x = f2bf(v.x); o.y = f2bf(v.y); o.z = f2bf(v.z); o.w = f2bf(v.w);
    ((ushort4*)dst)[j] = o;
  }
}

__device__ __forceinline__ void gl_lds16(const void* g, void* l){
  __builtin_amdgcn_global_load_lds(
      (const __attribute__((address_space(1))) unsigned int*)g,
      (__attribute__((address_space(3))) unsigned int*)l,
      16, 0, 0);
}

// C = A[M,K] * B[N,K]^T, bf16 in, tiles 128x128 (round-5 proven kernel).
// MODE 0: plain write to C[M,N] (LD=N), OUT type.
// MODE 1: qkv-split: cols<4096 -> C (=qk, LD 4096); cols>=4096 (V third) ->
//         VT[b][h][d][t]
template<int MODE, typename OUT>
__global__ __launch_bounds__(256) void gemm_bt(const u16* __restrict__ A,
                                               const u16* __restrict__ B,
                                               OUT* __restrict__ C,
                                               u16* __restrict__ VT,
                                               int M, int N, int K){
  __shared__ __align__(16) u16 lA[2][128*32];
  __shared__ __align__(16) u16 lB[2][128*32];
  const int tid  = threadIdx.x;
  const int lane = tid & 63;
  const int r16  = lane & 15;
  const int g4   = lane >> 4;
  const int wave = tid >> 6;
  const int wr = (wave >> 1) * 64, wc = (wave & 1) * 64;

  const int nwg = gridDim.x * gridDim.y;
  const int idl = blockIdx.y * gridDim.x + blockIdx.x;
  const int wg  = (idl & 7) * (nwg >> 3) + (idl >> 3);
  const int bx  = wg / gridDim.y, by = wg % gridDim.y;
  const int m0 = by * 128, n0 = bx * 128;

  const int srow = tid >> 2;          // 0..63
  const int scol = (tid & 3) << 3;    // 0,8,16,24

  f32x4 acc[4][4] = {};

  const int nk = K >> 5;
  int buf = 0;

  gl_lds16(&A[(size_t)(m0 + srow)*K + scol],      &lA[0][srow*32 + scol]);
  gl_lds16(&A[(size_t)(m0 + 64 + srow)*K + scol], &lA[0][(64+srow)*32 + scol]);
  gl_lds16(&B[(size_t)(n0 + srow)*K + scol],      &lB[0][srow*32 + scol]);
  gl_lds16(&B[(size_t)(n0 + 64 + srow)*K + scol], &lB[0][(64+srow)*32 + scol]);

  for (int kt = 0; kt < nk; ++kt){
    __syncthreads();
    if (kt + 1 < nk){
      const int k0 = (kt + 1) << 5;
      gl_lds16(&A[(size_t)(m0 + srow)*K + k0 + scol],      &lA[buf^1][srow*32 + scol]);
      gl_lds16(&A[(size_t)(m0 + 64 + srow)*K + k0 + scol], &lA[buf^1][(64+srow)*32 + scol]);
      gl_lds16(&B[(size_t)(n0 + srow)*K + k0 + scol],      &lB[buf^1][srow*32 + scol]);
      gl_lds16(&B[(size_t)(n0 + 64 + srow)*K + k0 + scol], &lB[buf^1][(64+srow)*32 + scol]);
    }
    short8 af[4], bfv[4];
    #pragma unroll
    for (int i=0;i<4;i++)
      af[i] = *(const short8*)&lA[buf][(wr + i*16 + r16)*32 + g4*8];
    #pragma unroll
    for (int j=0;j<4;j++)
      bfv[j] = *(const short8*)&lB[buf][(wc + j*16 + r16)*32 + g4*8];
    #pragma unroll
    for (int i=0;i<4;i++)
      #pragma unroll
      for (int j=0;j<4;j++)
        acc[i][j] = __builtin_amdgcn_mfma_f32_16x16x32_bf16(af[i], bfv[j], acc[i][j], 0,0,0);
    buf ^= 1;
  }

  if (MODE == 1 && n0 >= 4096){
    #pragma unroll
    for (int i=0;i<4;i++){
      const int m = m0 + wr + i*16 + g4*4;
      const int bb = m >> 11, t = m & 2047;
      #pragma unroll
      for (int j=0;j<4;j++){
        const int cv = n0 + wc + j*16 + r16 - 4096;
        const int h = cv >> 7, dl = cv & 127;
        ushort4 pack;
        pack.x = f2bf(acc[i][j][0]); pack.y = f2bf(acc[i][j][1]);
        pack.z = f2bf(acc[i][j][2]); pack.w = f2bf(acc[i][j][3]);
        *(ushort4*)&VT[(size_t)((bb<<4) + h)*262144 + (size_t)dl*2048 + t] = pack;
      }
    }
  } else {
    const int ldc = (MODE == 1) ? 4096 : N;
    #pragma unroll
    for (int i=0;i<4;i++){
      const int row = m0 + wr + i*16 + g4*4;
      #pragma unroll
      for (int j=0;j<4;j++){
        const int col = n0 + wc + j*16 + r16;
        #pragma unroll
        for (int r=0;r<4;r++){
          float v = acc[i][j][r];
          if constexpr (sizeof(OUT)==2) C[(size_t)(row+r)*ldc + col] = (OUT)f2bf(v);
          else                          C[(size_t)(row+r)*ldc + col] = (OUT)v;
        }
      }
    }
  }
}

// Flash attention, QBLK=128, KVBLK=64, 2-phase gl_lds pipeline (round-5 proven)
// + defer-max (T13). qk: [B*T][4096], vt: [B*16+h][128][2048].
__global__ __launch_bounds__(256) void attn_kernel(const u16* __restrict__ qk,
                                                   const u16* __restrict__ vt,
                                                   u16* __restrict__ y){
  __shared__ __align__(16) u16 Kl[2][64*128];
  __shared__ __align__(16) u16 Vl[2][128*64];
  __shared__ __align__(16) u16 Pl[4][32*64];

  const int tid = threadIdx.x, lane = tid & 63, wave = tid >> 6;
  const int r16 = lane & 15, g4 = lane >> 4;

  const int id = blockIdx.x;            // 0..511
  const int xk = id & 7,  kk = id >> 3;
  const int bh = 4*xk + (kk & 3);
  const int v5 = kk >> 2;
  const int qt = (v5 < 8) ? v5 : (23 - v5);

  const int b = bh >> 4, h = bh & 15;
  const int qcol = h*128, kcol = 2048 + h*128;
  const u16* vhead = vt + (size_t)bh * 262144;
  const float scale = 0.08838834764831845f;  // 1/sqrt(128)

  short8 qf[2][4];
  #pragma unroll
  for (int i=0;i<2;i++){
    const u16* qp = qk + (size_t)(b*T_SEQ + qt*128 + wave*32 + i*16 + r16)*4096 + qcol;
    #pragma unroll
    for (int c=0;c<4;c++) qf[i][c] = *(const short8*)&qp[g4*8 + c*32];
  }

  float mrow[2][4], lrow[2][4];
  #pragma unroll
  for (int i=0;i<2;i++)
    #pragma unroll
    for (int r=0;r<4;r++){ mrow[i][r] = -1e30f; lrow[i][r] = 0.f; }
  f32x4 o[2][8] = {};

  const int nt = 2*qt + 2;

  auto stage = [&](int sbuf, int t){
    const size_t kbase = (size_t)(b*T_SEQ + t*64)*4096 + kcol;
    #pragma unroll
    for (int c=0;c<4;c++){
      const int row0 = wave*16 + c*4;
      const int row  = row0 + g4;
      gl_lds16(&qk[kbase + (size_t)row*4096 + ((r16*8) ^ ((row&7)<<3))],
               &Kl[sbuf][row0*128]);
    }
    const int t0 = t*64;
    #pragma unroll
    for (int c=0;c<4;c++){
      const int idx = wave*4 + c;
      const int d   = idx*8 + (lane>>3);
      const int j8  = (lane&7)*8;
      gl_lds16(&vhead[(size_t)d*2048 + t0 + (j8 ^ ((d&7)<<3))],
               &Vl[sbuf][idx*512]);
    }
  };

  stage(0, 0);
  int cur = 0;

  for (int t = 0; t < nt; ++t){
    __syncthreads();
    if (t + 1 < nt) stage(cur^1, t+1);

    // ---- S = Q K^T : per wave 32q x 64kv
    float smat[2][4][4];
    #pragma unroll
    for (int cc=0;cc<4;cc++){
      const int krow = cc*16 + r16;
      const int sw = (krow & 7) << 3;
      short8 kf[4];
      #pragma unroll
      for (int dc=0;dc<4;dc++)
        kf[dc] = *(const short8*)&Kl[cur][krow*128 + ((g4*8 + dc*32) ^ sw)];
      #pragma unroll
      for (int i=0;i<2;i++){
        f32x4 sv = {0.f,0.f,0.f,0.f};
        #pragma unroll
        for (int dc=0;dc<4;dc++)
          sv = __builtin_amdgcn_mfma_f32_16x16x32_bf16(qf[i][dc], kf[dc], sv, 0,0,0);
        #pragma unroll
        for (int rr=0;rr<4;rr++) smat[i][cc][rr] = sv[rr] * scale;
      }
    }
    if (t >= 2*qt){
      #pragma unroll
      for (int cc=0;cc<4;cc++){
        const int kvl = (t - 2*qt)*64 + cc*16 + r16;
        #pragma unroll
        for (int i=0;i<2;i++)
          #pragma unroll
          for (int rr=0;rr<4;rr++){
            const int qi = wave*32 + i*16 + g4*4 + rr;
            if (kvl > qi) smat[i][cc][rr] = -1e30f;
          }
      }
    }

    // ---- online softmax with defer-max (T13): skip rescale when max growth<=8
    float pm[2][4];
    #pragma unroll
    for (int i=0;i<2;i++)
      #pragma unroll
      for (int rr=0;rr<4;rr++){
        float p0 = fmaxf(fmaxf(smat[i][0][rr], smat[i][1][rr]),
                         fmaxf(smat[i][2][rr], smat[i][3][rr]));
        #pragma unroll
        for (int off=1; off<16; off<<=1) p0 = fmaxf(p0, __shfl_xor(p0, off, 64));
        pm[i][rr] = p0;
      }
    bool need = false;
    #pragma unroll
    for (int i=0;i<2;i++)
      #pragma unroll
      for (int rr=0;rr<4;rr++) need = need || (pm[i][rr] > mrow[i][rr] + 8.f);
    if (__any(need)){   // wave-uniform branch
      #pragma unroll
      for (int i=0;i<2;i++)
        #pragma unroll
        for (int rr=0;rr<4;rr++){
          const float mnew = fmaxf(mrow[i][rr], pm[i][rr]);
          const float corr = __expf(mrow[i][rr] - mnew);
          mrow[i][rr] = mnew;
          lrow[i][rr] *= corr;
          #pragma unroll
          for (int n=0;n<8;n++) o[i][n][rr] *= corr;
        }
    }
    #pragma unroll
    for (int i=0;i<2;i++)
      #pragma unroll
      for (int rr=0;rr<4;rr++){
        float s0 = 0.f;
        #pragma unroll
        for (int cc=0;cc<4;cc++){
          const float p = __expf(smat[i][cc][rr] - mrow[i][rr]);
          smat[i][cc][rr] = p;
          s0 += p;
        }
        #pragma unroll
        for (int off=1; off<16; off<<=1) s0 += __shfl_xor(s0, off, 64);
        lrow[i][rr] += s0;
      }

    // ---- P -> LDS (bf16), wave-local
    #pragma unroll
    for (int i=0;i<2;i++)
      #pragma unroll
      for (int cc=0;cc<4;cc++)
        #pragma unroll
        for (int rr=0;rr<4;rr++){
          const int qr = i*16 + g4*4 + rr;
          Pl[wave][qr*64 + ((cc*16 + r16) ^ ((qr&7)<<3))] = f2bf(smat[i][cc][rr]);
        }
    asm volatile("s_waitcnt lgkmcnt(0)" ::: "memory");

    short8 pf[2][2];
    #pragma unroll
    for (int i=0;i<2;i++){
      const int qr = i*16 + r16;
      const int sw = (qr & 7) << 3;
      pf[i][0] = *(const short8*)&Pl[wave][qr*64 + ((g4*8)      ^ sw)];
      pf[i][1] = *(const short8*)&Pl[wave][qr*64 + ((g4*8 + 32) ^ sw)];
    }
    #pragma unroll
    for (int n=0;n<8;n++){
      const int vr = n*16 + r16;
      const int sw = (vr & 7) << 3;
      short8 vf0 = *(const short8*)&Vl[cur][vr*64 + ((g4*8)      ^ sw)];
      short8 vf1 = *(const short8*)&Vl[cur][vr*64 + ((g4*8 + 32) ^ sw)];
      #pragma unroll
      for (int i=0;i<2;i++){
        o[i][n] = __builtin_amdgcn_mfma_f32_16x16x32_bf16(pf[i][0], vf0, o[i][n], 0,0,0);
        o[i][n] = __builtin_amdgcn_mfma_f32_16x16x32_bf16(pf[i][1], vf1, o[i][n], 0,0,0);
      }
    }
    cur ^= 1;
  }

  #pragma unroll
  for (int i=0;i<2;i++){
    const size_t yr0 = (size_t)(b*T_SEQ + qt*128 + wave*32 + i*16 + g4*4) * C_DIM + h*128;
    #pragma unroll
    for (int n=0;n<8;n++)
      #pragma unroll
      for (int rr=0;rr<4;rr++){
        const float v = o[i][n][rr] / lrow[i][rr];
        y[yr0 + (size_t)rr*C_DIM + n*16 + r16] = f2bf(v);
      }
  }
}

extern "C" void kernel_launch(void* const* d_in, const int* in_sizes, int n_in,
                              void* d_out, int out_size, void* d_ws, size_t ws_size,
                              hipStream_t stream){
  const float* x  = (const float*)d_in[0];
  const float* wa = (const float*)d_in[1];
  const float* wp = (const float*)d_in[2];
  float* out = (float*)d_out;

  u16* ws  = (u16*)d_ws;
  u16* xb  = ws;                 //  8,388,608 elems (x bf16) — reused as yb later
  u16* wab = xb  + 8388608;      // 12,582,912 elems (w_attn bf16)
  u16* wpb = wab + 12582912;     //  4,194,304 elems (w_proj bf16)
  u16* qk  = wpb + 4194304;      // 16,777,216 elems ([4096][4096] Q|K)
  u16* vt  = qk  + 16777216;     //  8,388,608 elems ([32][128][2048] V^T)
  u16* yb  = xb;                 // alias: x dead after GEMM1

  hipLaunchKernelGGL(cvt3_kernel, dim3(2048), dim3(256), 0, stream,
                     x, wa, wp, xb, wab, wpb);

  // qkv projection with V-split epilogue
  hipLaunchKernelGGL((gemm_bt<1,u16>),   dim3(48,32), dim3(256), 0, stream,
                     xb, wab, qk, vt, 4096, 6144, 2048);
  hipLaunchKernelGGL(attn_kernel,        dim3(512),  dim3(256), 0, stream,
                     qk, vt, yb);
  hipLaunchKernelGGL((gemm_bt<0,float>), dim3(16,32), dim3(256), 0, stream,
                     yb, wpb, out, (u16*)nullptr, 4096, 2048, 2048);
}

// Round 13
// 292.928 us; speedup vs baseline: 1.1931x; 1.0451x over previous
//
#include <hip/hip_runtime.h>

typedef __attribute__((ext_vector_type(8))) short short8;
typedef __attribute__((ext_vector_type(4))) float f32x4;
typedef unsigned short u16;

#define T_SEQ 2048
#define C_DIM 2048

static __device__ __forceinline__ u16 f2bf(float f){
  unsigned u = __float_as_uint(f);
  u = (u + 0x7fffu + ((u >> 16) & 1u)) >> 16;
  return (u16)u;
}

// merged f32->bf16 convert for x, w_attn, w_proj
__global__ void cvt3_kernel(const float* __restrict__ x,
                            const float* __restrict__ wa,
                            const float* __restrict__ wp,
                            u16* __restrict__ xb, u16* __restrict__ wab,
                            u16* __restrict__ wpb){
  int idx = blockIdx.x * blockDim.x + threadIdx.x;
  int stride = gridDim.x * blockDim.x;
  for (int i = idx; i < 6291456; i += stride){
    const float* src; u16* dst; int j;
    if (i < 2097152){ src = x;  dst = xb;  j = i; }
    else if (i < 5242880){ src = wa; dst = wab; j = i - 2097152; }
    else { src = wp; dst = wpb; j = i - 5242880; }
    float4 v = ((const float4*)src)[j];
    ushort4 o;
    o.x = f2bf(v.x); o.y = f2bf(v.y); o.z = f2bf(v.z); o.w = f2bf(v.w);
    ((ushort4*)dst)[j] = o;
  }
}

__device__ __forceinline__ void gl_lds16(const void* g, void* l){
  __builtin_amdgcn_global_load_lds(
      (const __attribute__((address_space(1))) unsigned int*)g,
      (__attribute__((address_space(3))) unsigned int*)l,
      16, 0, 0);
}

// ------------- 128x256 BK=64 2-phase counted-vmcnt GEMM ---------------------
// 8 waves (2M x 4N), per-wave 64x64. LDS 96KB: 2dbuf x (A 16KB + B 32KB).
// ONE-PHASE-EARLY vmcnt ledger (each phase's ds_reads covered by the wait in
// the PREVIOUS phase):
//   prologue: stage [A0, B01_0, B23_0] -> vmcnt(2) retires A0,B01_0 -> barrier
//   phase A(t): reads A(t),B01(t); stage A(t+1),B01(t+1); vmcnt(4) retires
//               B23(t)   [outstanding 2+4=6 -> 4]  (covers phase B's reads)
//   phase B(t): reads B23(t); stage B23(t+1); vmcnt(2) retires A,B01(t+1)
//               [outstanding 4+2=6 -> 2]           (covers next phase A)
//   last tile: vmcnt(0)@A, none@B.
// FIX vs r11: stB2 half-coverage now MATCHES rdB halves — staging half h
// covers rows 64g + h*32 + {0..31} via row0 = (wave>>1)*64 + half*32 +
// (wave&1)*16 + c*8  (r11 staged wave*32 + half*16 + c*8, which interleaved
// halves and let phase A read rows still in flight -> 0.189 absmax).
// Swizzle elem ^= (row&7)<<3 on 128B rows; linear gl_lds dest + inverse-
// swizzled global source. MODE 0: plain C. MODE 1: qkv-split.
template<int MODE, typename OUT>
__global__ __launch_bounds__(512, 2) void gemm256(const u16* __restrict__ A,
                                                  const u16* __restrict__ B,
                                                  OUT* __restrict__ C,
                                                  u16* __restrict__ VT,
                                                  int M, int N, int K){
  __shared__ __align__(16) u16 lA[2][128*64];   // 32 KB
  __shared__ __align__(16) u16 lB[2][256*64];   // 64 KB
  const int tid  = threadIdx.x;
  const int lane = tid & 63;
  const int r16  = lane & 15;
  const int g4   = lane >> 4;
  const int wave = tid >> 6;                 // 0..7
  const int wm = wave >> 2, wn = wave & 3;   // 2M x 4N

  const int nwg = gridDim.x * gridDim.y;
  const int idl = blockIdx.y * gridDim.x + blockIdx.x;
  const int wg  = (idl & 7) * (nwg >> 3) + (idl >> 3);
  const int bx  = wg / gridDim.y, by = wg % gridDim.y;
  const int m0 = by * 128, n0 = bx * 256;

  f32x4 acc[4][4] = {};
  const int nt = K >> 6;

  auto stA = [&](int b, int t){
    #pragma unroll
    for (int c=0;c<2;c++){
      const int row0 = wave*16 + c*8;            // wave-uniform, covers 0..127
      const int row  = row0 + (lane>>3);
      const int cole = (((lane&7) ^ (row&7)) << 3);
      gl_lds16(&A[(size_t)(m0+row)*K + t*64 + cole], &lA[b][row0*64]);
    }
  };
  // half h covers rows 64g + h*32 + {0..31} for every 64-row group g
  auto stB2 = [&](int b, int t, int half){
    #pragma unroll
    for (int c=0;c<2;c++){
      const int row0 = (wave>>1)*64 + half*32 + (wave&1)*16 + c*8;
      const int row  = row0 + (lane>>3);
      const int cole = (((lane&7) ^ (row&7)) << 3);
      gl_lds16(&B[(size_t)(n0+row)*K + t*64 + cole], &lB[b][row0*64]);
    }
  };
  auto rdA = [&](short8 (&af)[4][2], int b){
    #pragma unroll
    for (int i=0;i<4;i++){
      const int R = wm*64 + i*16 + r16;
      #pragma unroll
      for (int ks=0;ks<2;ks++)
        af[i][ks] = *(const short8*)&lA[b][R*64 + ((g4*8 + ks*32) ^ ((R&7)<<3))];
    }
  };
  auto rdB = [&](short8 (&bf)[2][2], int b, int half){
    #pragma unroll
    for (int j=0;j<2;j++){
      const int R = wn*64 + half*32 + j*16 + r16;
      #pragma unroll
      for (int ks=0;ks<2;ks++)
        bf[j][ks] = *(const short8*)&lB[b][R*64 + ((g4*8 + ks*32) ^ ((R&7)<<3))];
    }
  };

  // prologue: stage tile 0; retire A0,B01_0 BEFORE any wave reads them
  stA(0,0); stB2(0,0,0); stB2(0,0,1);
  asm volatile("s_waitcnt vmcnt(2)" ::: "memory");
  __builtin_amdgcn_s_barrier();
  asm volatile("" ::: "memory");

  for (int t = 0; t < nt; ++t){
    const int cb = t & 1, nb = cb ^ 1;
    const bool more = (t + 1 < nt);
    short8 af[4][2], bf[2][2];

    // ---- phase A: (A, B-low). reads covered by prior vmcnt(2)+barrier
    rdA(af, cb); rdB(bf, cb, 0);
    if (more){
      stA(nb, t+1); stB2(nb, t+1, 0);
      asm volatile("s_waitcnt vmcnt(4)" ::: "memory");   // retires B23(t)
    } else {
      asm volatile("s_waitcnt vmcnt(0)" ::: "memory");
    }
    __builtin_amdgcn_s_barrier();
    asm volatile("s_waitcnt lgkmcnt(0)" ::: "memory");
    __builtin_amdgcn_sched_barrier(0);
    __builtin_amdgcn_s_setprio(1);
    #pragma unroll
    for (int i=0;i<4;i++)
      #pragma unroll
      for (int j=0;j<2;j++)
        #pragma unroll
        for (int ks=0;ks<2;ks++)
          acc[i][j] = __builtin_amdgcn_mfma_f32_16x16x32_bf16(af[i][ks], bf[j][ks], acc[i][j], 0,0,0);
    __builtin_amdgcn_s_setprio(0);
    __builtin_amdgcn_s_barrier();
    asm volatile("" ::: "memory");

    // ---- phase B: (A, B-high). reads covered by phase A's vmcnt(4)+barrier
    rdB(bf, cb, 1);
    if (more){
      stB2(nb, t+1, 1);
      asm volatile("s_waitcnt vmcnt(2)" ::: "memory");   // retires A,B01(t+1)
    }
    __builtin_amdgcn_s_barrier();
    asm volatile("s_waitcnt lgkmcnt(0)" ::: "memory");
    __builtin_amdgcn_sched_barrier(0);
    __builtin_amdgcn_s_setprio(1);
    #pragma unroll
    for (int i=0;i<4;i++)
      #pragma unroll
      for (int j=0;j<2;j++)
        #pragma unroll
        for (int ks=0;ks<2;ks++)
          acc[i][2+j] = __builtin_amdgcn_mfma_f32_16x16x32_bf16(af[i][ks], bf[j][ks], acc[i][2+j], 0,0,0);
    __builtin_amdgcn_s_setprio(0);
    __builtin_amdgcn_s_barrier();
    asm volatile("" ::: "memory");
  }

  if (MODE == 1 && n0 >= 4096){
    #pragma unroll
    for (int i=0;i<4;i++){
      const int m = m0 + wm*64 + i*16 + g4*4;
      const int bb = m >> 11, tt = m & 2047;
      #pragma unroll
      for (int j=0;j<4;j++){
        const int cv = n0 + wn*64 + j*16 + r16 - 4096;
        const int h = cv >> 7, dl = cv & 127;
        ushort4 pack;
        pack.x = f2bf(acc[i][j][0]); pack.y = f2bf(acc[i][j][1]);
        pack.z = f2bf(acc[i][j][2]); pack.w = f2bf(acc[i][j][3]);
        *(ushort4*)&VT[(size_t)((bb<<4) + h)*262144 + (size_t)dl*2048 + tt] = pack;
      }
    }
  } else {
    const int ldc = (MODE == 1) ? 4096 : N;
    #pragma unroll
    for (int i=0;i<4;i++){
      const int row = m0 + wm*64 + i*16 + g4*4;
      #pragma unroll
      for (int j=0;j<4;j++){
        const int col = n0 + wn*64 + j*16 + r16;
        #pragma unroll
        for (int r=0;r<4;r++){
          float v = acc[i][j][r];
          if constexpr (sizeof(OUT)==2) C[(size_t)(row+r)*ldc + col] = (OUT)f2bf(v);
          else                          C[(size_t)(row+r)*ldc + col] = (OUT)v;
        }
      }
    }
  }
}

// Flash attention, QBLK=128, KVBLK=64, 2-phase gl_lds pipeline + defer-max.
__global__ __launch_bounds__(256) void attn_kernel(const u16* __restrict__ qk,
                                                   const u16* __restrict__ vt,
                                                   u16* __restrict__ y){
  __shared__ __align__(16) u16 Kl[2][64*128];
  __shared__ __align__(16) u16 Vl[2][128*64];
  __shared__ __align__(16) u16 Pl[4][32*64];

  const int tid = threadIdx.x, lane = tid & 63, wave = tid >> 6;
  const int r16 = lane & 15, g4 = lane >> 4;

  const int id = blockIdx.x;            // 0..511
  const int xk = id & 7,  kk = id >> 3;
  const int bh = 4*xk + (kk & 3);
  const int v5 = kk >> 2;
  const int qt = (v5 < 8) ? v5 : (23 - v5);

  const int b = bh >> 4, h = bh & 15;
  const int qcol = h*128, kcol = 2048 + h*128;
  const u16* vhead = vt + (size_t)bh * 262144;
  const float scale = 0.08838834764831845f;

  short8 qf[2][4];
  #pragma unroll
  for (int i=0;i<2;i++){
    const u16* qp = qk + (size_t)(b*T_SEQ + qt*128 + wave*32 + i*16 + r16)*4096 + qcol;
    #pragma unroll
    for (int c=0;c<4;c++) qf[i][c] = *(const short8*)&qp[g4*8 + c*32];
  }

  float mrow[2][4], lrow[2][4];
  #pragma unroll
  for (int i=0;i<2;i++)
    #pragma unroll
    for (int r=0;r<4;r++){ mrow[i][r] = -1e30f; lrow[i][r] = 0.f; }
  f32x4 o[2][8] = {};

  const int nt = 2*qt + 2;

  auto stage = [&](int sbuf, int t){
    const size_t kbase = (size_t)(b*T_SEQ + t*64)*4096 + kcol;
    #pragma unroll
    for (int c=0;c<4;c++){
      const int row0 = wave*16 + c*4;
      const int row  = row0 + g4;
      gl_lds16(&qk[kbase + (size_t)row*4096 + ((r16*8) ^ ((row&7)<<3))],
               &Kl[sbuf][row0*128]);
    }
    const int t0 = t*64;
    #pragma unroll
    for (int c=0;c<4;c++){
      const int idx = wave*4 + c;
      const int d   = idx*8 + (lane>>3);
      const int j8  = (lane&7)*8;
      gl_lds16(&vhead[(size_t)d*2048 + t0 + (j8 ^ ((d&7)<<3))],
               &Vl[sbuf][idx*512]);
    }
  };

  stage(0, 0);
  int cur = 0;

  for (int t = 0; t < nt; ++t){
    __syncthreads();
    if (t + 1 < nt) stage(cur^1, t+1);

    float smat[2][4][4];
    #pragma unroll
    for (int cc=0;cc<4;cc++){
      const int krow = cc*16 + r16;
      const int sw = (krow & 7) << 3;
      short8 kf[4];
      #pragma unroll
      for (int dc=0;dc<4;dc++)
        kf[dc] = *(const short8*)&Kl[cur][krow*128 + ((g4*8 + dc*32) ^ sw)];
      #pragma unroll
      for (int i=0;i<2;i++){
        f32x4 sv = {0.f,0.f,0.f,0.f};
        #pragma unroll
        for (int dc=0;dc<4;dc++)
          sv = __builtin_amdgcn_mfma_f32_16x16x32_bf16(qf[i][dc], kf[dc], sv, 0,0,0);
        #pragma unroll
        for (int rr=0;rr<4;rr++) smat[i][cc][rr] = sv[rr] * scale;
      }
    }
    if (t >= 2*qt){
      #pragma unroll
      for (int cc=0;cc<4;cc++){
        const int kvl = (t - 2*qt)*64 + cc*16 + r16;
        #pragma unroll
        for (int i=0;i<2;i++)
          #pragma unroll
          for (int rr=0;rr<4;rr++){
            const int qi = wave*32 + i*16 + g4*4 + rr;
            if (kvl > qi) smat[i][cc][rr] = -1e30f;
          }
      }
    }

    float pm[2][4];
    #pragma unroll
    for (int i=0;i<2;i++)
      #pragma unroll
      for (int rr=0;rr<4;rr++){
        float p0 = fmaxf(fmaxf(smat[i][0][rr], smat[i][1][rr]),
                         fmaxf(smat[i][2][rr], smat[i][3][rr]));
        #pragma unroll
        for (int off=1; off<16; off<<=1) p0 = fmaxf(p0, __shfl_xor(p0, off, 64));
        pm[i][rr] = p0;
      }
    bool need = false;
    #pragma unroll
    for (int i=0;i<2;i++)
      #pragma unroll
      for (int rr=0;rr<4;rr++) need = need || (pm[i][rr] > mrow[i][rr] + 8.f);
    if (__any(need)){
      #pragma unroll
      for (int i=0;i<2;i++)
        #pragma unroll
        for (int rr=0;rr<4;rr++){
          const float mnew = fmaxf(mrow[i][rr], pm[i][rr]);
          const float corr = __expf(mrow[i][rr] - mnew);
          mrow[i][rr] = mnew;
          lrow[i][rr] *= corr;
          #pragma unroll
          for (int n=0;n<8;n++) o[i][n][rr] *= corr;
        }
    }
    #pragma unroll
    for (int i=0;i<2;i++)
      #pragma unroll
      for (int rr=0;rr<4;rr++){
        float s0 = 0.f;
        #pragma unroll
        for (int cc=0;cc<4;cc++){
          const float p = __expf(smat[i][cc][rr] - mrow[i][rr]);
          smat[i][cc][rr] = p;
          s0 += p;
        }
        #pragma unroll
        for (int off=1; off<16; off<<=1) s0 += __shfl_xor(s0, off, 64);
        lrow[i][rr] += s0;
      }

    #pragma unroll
    for (int i=0;i<2;i++)
      #pragma unroll
      for (int cc=0;cc<4;cc++)
        #pragma unroll
        for (int rr=0;rr<4;rr++){
          const int qr = i*16 + g4*4 + rr;
          Pl[wave][qr*64 + ((cc*16 + r16) ^ ((qr&7)<<3))] = f2bf(smat[i][cc][rr]);
        }
    asm volatile("s_waitcnt lgkmcnt(0)" ::: "memory");

    short8 pf[2][2];
    #pragma unroll
    for (int i=0;i<2;i++){
      const int qr = i*16 + r16;
      const int sw = (qr & 7) << 3;
      pf[i][0] = *(const short8*)&Pl[wave][qr*64 + ((g4*8)      ^ sw)];
      pf[i][1] = *(const short8*)&Pl[wave][qr*64 + ((g4*8 + 32) ^ sw)];
    }
    #pragma unroll
    for (int n=0;n<8;n++){
      const int vr = n*16 + r16;
      const int sw = (vr & 7) << 3;
      short8 vf0 = *(const short8*)&Vl[cur][vr*64 + ((g4*8)      ^ sw)];
      short8 vf1 = *(const short8*)&Vl[cur][vr*64 + ((g4*8 + 32) ^ sw)];
      #pragma unroll
      for (int i=0;i<2;i++){
        o[i][n] = __builtin_amdgcn_mfma_f32_16x16x32_bf16(pf[i][0], vf0, o[i][n], 0,0,0);
        o[i][n] = __builtin_amdgcn_mfma_f32_16x16x32_bf16(pf[i][1], vf1, o[i][n], 0,0,0);
      }
    }
    cur ^= 1;
  }

  #pragma unroll
  for (int i=0;i<2;i++){
    const size_t yr0 = (size_t)(b*T_SEQ + qt*128 + wave*32 + i*16 + g4*4) * C_DIM + h*128;
    #pragma unroll
    for (int n=0;n<8;n++)
      #pragma unroll
      for (int rr=0;rr<4;rr++){
        const float v = o[i][n][rr] / lrow[i][rr];
        y[yr0 + (size_t)rr*C_DIM + n*16 + r16] = f2bf(v);
      }
  }
}

extern "C" void kernel_launch(void* const* d_in, const int* in_sizes, int n_in,
                              void* d_out, int out_size, void* d_ws, size_t ws_size,
                              hipStream_t stream){
  const float* x  = (const float*)d_in[0];
  const float* wa = (const float*)d_in[1];
  const float* wp = (const float*)d_in[2];
  float* out = (float*)d_out;

  u16* ws  = (u16*)d_ws;
  u16* xb  = ws;                 //  8,388,608 elems (x bf16) — reused as yb later
  u16* wab = xb  + 8388608;      // 12,582,912 elems (w_attn bf16)
  u16* wpb = wab + 12582912;     //  4,194,304 elems (w_proj bf16)
  u16* qk  = wpb + 4194304;      // 16,777,216 elems ([4096][4096] Q|K)
  u16* vt  = qk  + 16777216;     //  8,388,608 elems ([32][128][2048] V^T)
  u16* yb  = xb;                 // alias: x dead after GEMM1

  hipLaunchKernelGGL(cvt3_kernel, dim3(2048), dim3(256), 0, stream,
                     x, wa, wp, xb, wab, wpb);

  // qkv projection: grid 24 n-tiles(256) x 32 m-tiles(128) = 768 = 3 x 256 CUs
  hipLaunchKernelGGL((gemm256<1,u16>),   dim3(24,32), dim3(512), 0, stream,
                     xb, wab, qk, vt, 4096, 6144, 2048);
  hipLaunchKernelGGL(attn_kernel,        dim3(512),  dim3(256), 0, stream,
                     qk, vt, yb);
  // out projection: grid 8 n-tiles(256) x 32 m-tiles(128) = 256 = 1 x 256 CUs
  hipLaunchKernelGGL((gemm256<0,float>), dim3(8,32),  dim3(512), 0, stream,
                     yb, wpb, out, (u16*)nullptr, 4096, 2048, 2048);
}

// Round 14
// 286.003 us; speedup vs baseline: 1.2220x; 1.0242x over previous
//
#include <hip/hip_runtime.h>

typedef __attribute__((ext_vector_type(8))) short short8;
typedef __attribute__((ext_vector_type(4))) float f32x4;
typedef unsigned short u16;

#define T_SEQ 2048
#define C_DIM 2048

static __device__ __forceinline__ u16 f2bf(float f){
  unsigned u = __float_as_uint(f);
  u = (u + 0x7fffu + ((u >> 16) & 1u)) >> 16;
  return (u16)u;
}

// merged f32->bf16 convert for x, w_attn, w_proj
__global__ void cvt3_kernel(const float* __restrict__ x,
                            const float* __restrict__ wa,
                            const float* __restrict__ wp,
                            u16* __restrict__ xb, u16* __restrict__ wab,
                            u16* __restrict__ wpb){
  int idx = blockIdx.x * blockDim.x + threadIdx.x;
  int stride = gridDim.x * blockDim.x;
  for (int i = idx; i < 6291456; i += stride){
    const float* src; u16* dst; int j;
    if (i < 2097152){ src = x;  dst = xb;  j = i; }
    else if (i < 5242880){ src = wa; dst = wab; j = i - 2097152; }
    else { src = wp; dst = wpb; j = i - 5242880; }
    float4 v = ((const float4*)src)[j];
    ushort4 o;
    o.x = f2bf(v.x); o.y = f2bf(v.y); o.z = f2bf(v.z); o.w = f2bf(v.w);
    ((ushort4*)dst)[j] = o;
  }
}

__device__ __forceinline__ void gl_lds16(const void* g, void* l){
  __builtin_amdgcn_global_load_lds(
      (const __attribute__((address_space(1))) unsigned int*)g,
      (__attribute__((address_space(3))) unsigned int*)l,
      16, 0, 0);
}

// ------------- 128x128 BK=64 2-phase counted-vmcnt GEMM, 2 blocks/CU --------
// 4 waves (2M x 2N), per-wave 64x64. LDS 64KB: 2dbuf x (A 16KB + B 16KB)
// -> 2 blocks/CU for cross-block latency hiding (the r13 engine had 96KB ->
// 1 block/CU -> every stall exposed).
// Per-wave schedule identical to r13: phase A {rdA(8)+rdB0(4); stage A(t+1),
// B0(t+1); vmcnt; barrier; lgkm; 16 MFMA; barrier}, phase B {rdB1(4); stage
// B1(t+1); vmcnt; barrier; lgkm; 16 MFMA; barrier}.
// ONE-PHASE-EARLY vmcnt ledger (per-wave stage counts: A=4, B0=2, B1=2):
//   prologue: stage [A0(4), B0_0(2), B1_0(2)] -> vmcnt(2) retires A0,B0_0
//   phase A(t): stage A(t+1)+B0(t+1) [FIFO: B1(t)2, A(t+1)4, B0(t+1)2];
//               vmcnt(6) retires B1(t)          (covers phase B's reads)
//   phase B(t): stage B1(t+1) [FIFO: A(t+1)4, B0(t+1)2, B1(t+1)2];
//               vmcnt(2) retires A(t+1),B0(t+1) (covers next phase A)
//   last tile: vmcnt(0)@A, none@B.
// Staging/read coverage verified: stA covers rows 0..127 (4 waves x 32),
// stB2 half h covers rows {h*32..h*32+31} u {64+h*32..} == rdB(half) rows
// wn*64 + half*32 + {0..31} over wn in {0,1}.
// Swizzle elem ^= (row&7)<<3; linear gl_lds dest + inverse-swizzled source.
// MODE 0: plain C. MODE 1: qkv-split (cols<4096 -> qk LD4096; else VT).
template<int MODE, typename OUT>
__global__ __launch_bounds__(256, 2) void gemm256(const u16* __restrict__ A,
                                                  const u16* __restrict__ B,
                                                  OUT* __restrict__ C,
                                                  u16* __restrict__ VT,
                                                  int M, int N, int K){
  __shared__ __align__(16) u16 lA[2][128*64];   // 32 KB
  __shared__ __align__(16) u16 lB[2][128*64];   // 32 KB
  const int tid  = threadIdx.x;
  const int lane = tid & 63;
  const int r16  = lane & 15;
  const int g4   = lane >> 4;
  const int wave = tid >> 6;                 // 0..3
  const int wm = wave >> 1, wn = wave & 1;   // 2M x 2N

  const int nwg = gridDim.x * gridDim.y;
  const int idl = blockIdx.y * gridDim.x + blockIdx.x;
  const int wg  = (idl & 7) * (nwg >> 3) + (idl >> 3);
  const int bx  = wg / gridDim.y, by = wg % gridDim.y;
  const int m0 = by * 128, n0 = bx * 128;

  f32x4 acc[4][4] = {};
  const int nt = K >> 6;

  auto stA = [&](int b, int t){
    #pragma unroll
    for (int c=0;c<4;c++){
      const int row0 = wave*32 + c*8;            // wave-uniform, covers 0..127
      const int row  = row0 + (lane>>3);
      const int cole = (((lane&7) ^ (row&7)) << 3);
      gl_lds16(&A[(size_t)(m0+row)*K + t*64 + cole], &lA[b][row0*64]);
    }
  };
  // half h covers rows 64g + h*32 + {0..31} for g in {0,1}
  auto stB2 = [&](int b, int t, int half){
    #pragma unroll
    for (int c=0;c<2;c++){
      const int row0 = (wave>>1)*64 + half*32 + (wave&1)*16 + c*8;
      const int row  = row0 + (lane>>3);
      const int cole = (((lane&7) ^ (row&7)) << 3);
      gl_lds16(&B[(size_t)(n0+row)*K + t*64 + cole], &lB[b][row0*64]);
    }
  };
  auto rdA = [&](short8 (&af)[4][2], int b){
    #pragma unroll
    for (int i=0;i<4;i++){
      const int R = wm*64 + i*16 + r16;
      #pragma unroll
      for (int ks=0;ks<2;ks++)
        af[i][ks] = *(const short8*)&lA[b][R*64 + ((g4*8 + ks*32) ^ ((R&7)<<3))];
    }
  };
  auto rdB = [&](short8 (&bf)[2][2], int b, int half){
    #pragma unroll
    for (int j=0;j<2;j++){
      const int R = wn*64 + half*32 + j*16 + r16;
      #pragma unroll
      for (int ks=0;ks<2;ks++)
        bf[j][ks] = *(const short8*)&lB[b][R*64 + ((g4*8 + ks*32) ^ ((R&7)<<3))];
    }
  };

  // prologue: stage tile 0; retire A0,B0_0 BEFORE any wave reads them
  stA(0,0); stB2(0,0,0); stB2(0,0,1);
  asm volatile("s_waitcnt vmcnt(2)" ::: "memory");
  __builtin_amdgcn_s_barrier();
  asm volatile("" ::: "memory");

  for (int t = 0; t < nt; ++t){
    const int cb = t & 1, nb = cb ^ 1;
    const bool more = (t + 1 < nt);
    short8 af[4][2], bf[2][2];

    // ---- phase A: (A, B-low). reads covered by prior vmcnt(2)+barrier
    rdA(af, cb); rdB(bf, cb, 0);
    if (more){
      stA(nb, t+1); stB2(nb, t+1, 0);
      asm volatile("s_waitcnt vmcnt(6)" ::: "memory");   // retires B1(t)
    } else {
      asm volatile("s_waitcnt vmcnt(0)" ::: "memory");
    }
    __builtin_amdgcn_s_barrier();
    asm volatile("s_waitcnt lgkmcnt(0)" ::: "memory");
    __builtin_amdgcn_sched_barrier(0);
    __builtin_amdgcn_s_setprio(1);
    #pragma unroll
    for (int i=0;i<4;i++)
      #pragma unroll
      for (int j=0;j<2;j++)
        #pragma unroll
        for (int ks=0;ks<2;ks++)
          acc[i][j] = __builtin_amdgcn_mfma_f32_16x16x32_bf16(af[i][ks], bf[j][ks], acc[i][j], 0,0,0);
    __builtin_amdgcn_s_setprio(0);
    __builtin_amdgcn_s_barrier();
    asm volatile("" ::: "memory");

    // ---- phase B: (A, B-high). reads covered by phase A's vmcnt(6)+barrier
    rdB(bf, cb, 1);
    if (more){
      stB2(nb, t+1, 1);
      asm volatile("s_waitcnt vmcnt(2)" ::: "memory");   // retires A,B0(t+1)
    }
    __builtin_amdgcn_s_barrier();
    asm volatile("s_waitcnt lgkmcnt(0)" ::: "memory");
    __builtin_amdgcn_sched_barrier(0);
    __builtin_amdgcn_s_setprio(1);
    #pragma unroll
    for (int i=0;i<4;i++)
      #pragma unroll
      for (int j=0;j<2;j++)
        #pragma unroll
        for (int ks=0;ks<2;ks++)
          acc[i][2+j] = __builtin_amdgcn_mfma_f32_16x16x32_bf16(af[i][ks], bf[j][ks], acc[i][2+j], 0,0,0);
    __builtin_amdgcn_s_setprio(0);
    __builtin_amdgcn_s_barrier();
    asm volatile("" ::: "memory");
  }

  if (MODE == 1 && n0 >= 4096){
    #pragma unroll
    for (int i=0;i<4;i++){
      const int m = m0 + wm*64 + i*16 + g4*4;
      const int bb = m >> 11, tt = m & 2047;
      #pragma unroll
      for (int j=0;j<4;j++){
        const int cv = n0 + wn*64 + j*16 + r16 - 4096;
        const int h = cv >> 7, dl = cv & 127;
        ushort4 pack;
        pack.x = f2bf(acc[i][j][0]); pack.y = f2bf(acc[i][j][1]);
        pack.z = f2bf(acc[i][j][2]); pack.w = f2bf(acc[i][j][3]);
        *(ushort4*)&VT[(size_t)((bb<<4) + h)*262144 + (size_t)dl*2048 + tt] = pack;
      }
    }
  } else {
    const int ldc = (MODE == 1) ? 4096 : N;
    #pragma unroll
    for (int i=0;i<4;i++){
      const int row = m0 + wm*64 + i*16 + g4*4;
      #pragma unroll
      for (int j=0;j<4;j++){
        const int col = n0 + wn*64 + j*16 + r16;
        #pragma unroll
        for (int r=0;r<4;r++){
          float v = acc[i][j][r];
          if constexpr (sizeof(OUT)==2) C[(size_t)(row+r)*ldc + col] = (OUT)f2bf(v);
          else                          C[(size_t)(row+r)*ldc + col] = (OUT)v;
        }
      }
    }
  }
}

// Flash attention, QBLK=128, KVBLK=64, 2-phase gl_lds pipeline + defer-max.
__global__ __launch_bounds__(256) void attn_kernel(const u16* __restrict__ qk,
                                                   const u16* __restrict__ vt,
                                                   u16* __restrict__ y){
  __shared__ __align__(16) u16 Kl[2][64*128];
  __shared__ __align__(16) u16 Vl[2][128*64];
  __shared__ __align__(16) u16 Pl[4][32*64];

  const int tid = threadIdx.x, lane = tid & 63, wave = tid >> 6;
  const int r16 = lane & 15, g4 = lane >> 4;

  const int id = blockIdx.x;            // 0..511
  const int xk = id & 7,  kk = id >> 3;
  const int bh = 4*xk + (kk & 3);
  const int v5 = kk >> 2;
  const int qt = (v5 < 8) ? v5 : (23 - v5);

  const int b = bh >> 4, h = bh & 15;
  const int qcol = h*128, kcol = 2048 + h*128;
  const u16* vhead = vt + (size_t)bh * 262144;
  const float scale = 0.08838834764831845f;

  short8 qf[2][4];
  #pragma unroll
  for (int i=0;i<2;i++){
    const u16* qp = qk + (size_t)(b*T_SEQ + qt*128 + wave*32 + i*16 + r16)*4096 + qcol;
    #pragma unroll
    for (int c=0;c<4;c++) qf[i][c] = *(const short8*)&qp[g4*8 + c*32];
  }

  float mrow[2][4], lrow[2][4];
  #pragma unroll
  for (int i=0;i<2;i++)
    #pragma unroll
    for (int r=0;r<4;r++){ mrow[i][r] = -1e30f; lrow[i][r] = 0.f; }
  f32x4 o[2][8] = {};

  const int nt = 2*qt + 2;

  auto stage = [&](int sbuf, int t){
    const size_t kbase = (size_t)(b*T_SEQ + t*64)*4096 + kcol;
    #pragma unroll
    for (int c=0;c<4;c++){
      const int row0 = wave*16 + c*4;
      const int row  = row0 + g4;
      gl_lds16(&qk[kbase + (size_t)row*4096 + ((r16*8) ^ ((row&7)<<3))],
               &Kl[sbuf][row0*128]);
    }
    const int t0 = t*64;
    #pragma unroll
    for (int c=0;c<4;c++){
      const int idx = wave*4 + c;
      const int d   = idx*8 + (lane>>3);
      const int j8  = (lane&7)*8;
      gl_lds16(&vhead[(size_t)d*2048 + t0 + (j8 ^ ((d&7)<<3))],
               &Vl[sbuf][idx*512]);
    }
  };

  stage(0, 0);
  int cur = 0;

  for (int t = 0; t < nt; ++t){
    __syncthreads();
    if (t + 1 < nt) stage(cur^1, t+1);

    float smat[2][4][4];
    #pragma unroll
    for (int cc=0;cc<4;cc++){
      const int krow = cc*16 + r16;
      const int sw = (krow & 7) << 3;
      short8 kf[4];
      #pragma unroll
      for (int dc=0;dc<4;dc++)
        kf[dc] = *(const short8*)&Kl[cur][krow*128 + ((g4*8 + dc*32) ^ sw)];
      #pragma unroll
      for (int i=0;i<2;i++){
        f32x4 sv = {0.f,0.f,0.f,0.f};
        #pragma unroll
        for (int dc=0;dc<4;dc++)
          sv = __builtin_amdgcn_mfma_f32_16x16x32_bf16(qf[i][dc], kf[dc], sv, 0,0,0);
        #pragma unroll
        for (int rr=0;rr<4;rr++) smat[i][cc][rr] = sv[rr] * scale;
      }
    }
    if (t >= 2*qt){
      #pragma unroll
      for (int cc=0;cc<4;cc++){
        const int kvl = (t - 2*qt)*64 + cc*16 + r16;
        #pragma unroll
        for (int i=0;i<2;i++)
          #pragma unroll
          for (int rr=0;rr<4;rr++){
            const int qi = wave*32 + i*16 + g4*4 + rr;
            if (kvl > qi) smat[i][cc][rr] = -1e30f;
          }
      }
    }

    float pm[2][4];
    #pragma unroll
    for (int i=0;i<2;i++)
      #pragma unroll
      for (int rr=0;rr<4;rr++){
        float p0 = fmaxf(fmaxf(smat[i][0][rr], smat[i][1][rr]),
                         fmaxf(smat[i][2][rr], smat[i][3][rr]));
        #pragma unroll
        for (int off=1; off<16; off<<=1) p0 = fmaxf(p0, __shfl_xor(p0, off, 64));
        pm[i][rr] = p0;
      }
    bool need = false;
    #pragma unroll
    for (int i=0;i<2;i++)
      #pragma unroll
      for (int rr=0;rr<4;rr++) need = need || (pm[i][rr] > mrow[i][rr] + 8.f);
    if (__any(need)){
      #pragma unroll
      for (int i=0;i<2;i++)
        #pragma unroll
        for (int rr=0;rr<4;rr++){
          const float mnew = fmaxf(mrow[i][rr], pm[i][rr]);
          const float corr = __expf(mrow[i][rr] - mnew);
          mrow[i][rr] = mnew;
          lrow[i][rr] *= corr;
          #pragma unroll
          for (int n=0;n<8;n++) o[i][n][rr] *= corr;
        }
    }
    #pragma unroll
    for (int i=0;i<2;i++)
      #pragma unroll
      for (int rr=0;rr<4;rr++){
        float s0 = 0.f;
        #pragma unroll
        for (int cc=0;cc<4;cc++){
          const float p = __expf(smat[i][cc][rr] - mrow[i][rr]);
          smat[i][cc][rr] = p;
          s0 += p;
        }
        #pragma unroll
        for (int off=1; off<16; off<<=1) s0 += __shfl_xor(s0, off, 64);
        lrow[i][rr] += s0;
      }

    #pragma unroll
    for (int i=0;i<2;i++)
      #pragma unroll
      for (int cc=0;cc<4;cc++)
        #pragma unroll
        for (int rr=0;rr<4;rr++){
          const int qr = i*16 + g4*4 + rr;
          Pl[wave][qr*64 + ((cc*16 + r16) ^ ((qr&7)<<3))] = f2bf(smat[i][cc][rr]);
        }
    asm volatile("s_waitcnt lgkmcnt(0)" ::: "memory");

    short8 pf[2][2];
    #pragma unroll
    for (int i=0;i<2;i++){
      const int qr = i*16 + r16;
      const int sw = (qr & 7) << 3;
      pf[i][0] = *(const short8*)&Pl[wave][qr*64 + ((g4*8)      ^ sw)];
      pf[i][1] = *(const short8*)&Pl[wave][qr*64 + ((g4*8 + 32) ^ sw)];
    }
    #pragma unroll
    for (int n=0;n<8;n++){
      const int vr = n*16 + r16;
      const int sw = (vr & 7) << 3;
      short8 vf0 = *(const short8*)&Vl[cur][vr*64 + ((g4*8)      ^ sw)];
      short8 vf1 = *(const short8*)&Vl[cur][vr*64 + ((g4*8 + 32) ^ sw)];
      #pragma unroll
      for (int i=0;i<2;i++){
        o[i][n] = __builtin_amdgcn_mfma_f32_16x16x32_bf16(pf[i][0], vf0, o[i][n], 0,0,0);
        o[i][n] = __builtin_amdgcn_mfma_f32_16x16x32_bf16(pf[i][1], vf1, o[i][n], 0,0,0);
      }
    }
    cur ^= 1;
  }

  #pragma unroll
  for (int i=0;i<2;i++){
    const size_t yr0 = (size_t)(b*T_SEQ + qt*128 + wave*32 + i*16 + g4*4) * C_DIM + h*128;
    #pragma unroll
    for (int n=0;n<8;n++)
      #pragma unroll
      for (int rr=0;rr<4;rr++){
        const float v = o[i][n][rr] / lrow[i][rr];
        y[yr0 + (size_t)rr*C_DIM + n*16 + r16] = f2bf(v);
      }
  }
}

extern "C" void kernel_launch(void* const* d_in, const int* in_sizes, int n_in,
                              void* d_out, int out_size, void* d_ws, size_t ws_size,
                              hipStream_t stream){
  const float* x  = (const float*)d_in[0];
  const float* wa = (const float*)d_in[1];
  const float* wp = (const float*)d_in[2];
  float* out = (float*)d_out;

  u16* ws  = (u16*)d_ws;
  u16* xb  = ws;                 //  8,388,608 elems (x bf16) — reused as yb later
  u16* wab = xb  + 8388608;      // 12,582,912 elems (w_attn bf16)
  u16* wpb = wab + 12582912;     //  4,194,304 elems (w_proj bf16)
  u16* qk  = wpb + 4194304;      // 16,777,216 elems ([4096][4096] Q|K)
  u16* vt  = qk  + 16777216;     //  8,388,608 elems ([32][128][2048] V^T)
  u16* yb  = xb;                 // alias: x dead after GEMM1

  hipLaunchKernelGGL(cvt3_kernel, dim3(2048), dim3(256), 0, stream,
                     x, wa, wp, xb, wab, wpb);

  // qkv projection: grid 48 n-tiles(128) x 32 m-tiles(128) = 1536 = 3 rounds @ 2/CU
  hipLaunchKernelGGL((gemm256<1,u16>),   dim3(48,32), dim3(256), 0, stream,
                     xb, wab, qk, vt, 4096, 6144, 2048);
  hipLaunchKernelGGL(attn_kernel,        dim3(512),  dim3(256), 0, stream,
                     qk, vt, yb);
  // out projection: grid 16 x 32 = 512 = 1 round @ 2/CU
  hipLaunchKernelGGL((gemm256<0,float>), dim3(16,32), dim3(256), 0, stream,
                     yb, wpb, out, (u16*)nullptr, 4096, 2048, 2048);
}